// Round 5
// baseline (473.609 us; speedup 1.0000x reference)
//
#include <hip/hip_runtime.h>
#include <math.h>

#define NH 16
#define NKV 8
#define HDIM 128
#define SEQ 2048
#define DMODEL 2048

typedef int   v4i __attribute__((ext_vector_type(4)));
typedef float v4f __attribute__((ext_vector_type(4)));
typedef __bf16 v8bf __attribute__((ext_vector_type(8)));

static constexpr float SM_SCALE = 0.08838834764831843f; // 128**-0.5

#define GLOBP(p) (__attribute__((address_space(1))) void*)(p)
#define LDSP(p)  (__attribute__((address_space(3))) void*)(p)
#define ASYNC16(g, l) __builtin_amdgcn_global_load_lds(GLOBP(g), LDSP(l), 16, 0, 0)

// Fragment-tiled i8 layout for X[R][K] (R%16==0, K%64==0):
// frag (r>>4, k>>6) is 1024B; within: byte = ((k>>4)&3)*256 + (r&15)*16 + (k&15).
// A wave fragment read/ASYNC16 is then base + lane*16 -> fully coalesced 1KB.
__device__ __forceinline__ size_t gt_addr(int r, int k, int K) {
    return ((size_t)((r >> 4) * (K >> 6) + (k >> 6)) << 10) + (size_t)((((k >> 4) & 3) << 8)
         + ((r & 15) << 4) + (k & 15));
}

// ---------------- per-row symmetric int8 quant: tiled int8 out + scale ----------------
__global__ __launch_bounds__(256) void row_quant_k(const float* __restrict__ in,
        signed char* __restrict__ out, float* __restrict__ scale, int cols) {
    int row = blockIdx.x;
    const float4* x4 = (const float4*)(in + (size_t)row * cols);
    int n4 = cols >> 2;
    int tid = threadIdx.x;
    float amax = 0.f;
    for (int c = tid; c < n4; c += 256) {
        float4 v = x4[c];
        amax = fmaxf(amax, fmaxf(fmaxf(fabsf(v.x), fabsf(v.y)),
                                 fmaxf(fabsf(v.z), fabsf(v.w))));
    }
#pragma unroll
    for (int m = 32; m; m >>= 1) amax = fmaxf(amax, __shfl_xor(amax, m));
    __shared__ float red[4];
    if ((tid & 63) == 0) red[tid >> 6] = amax;
    __syncthreads();
    float a = fmaxf(fmaxf(red[0], red[1]), fmaxf(red[2], red[3]));
    float s = fmaxf(a / 127.0f, 1e-8f);
    if (tid == 0) scale[row] = s;
    for (int c = tid; c < n4; c += 256) {
        float4 v = x4[c];
        int b0 = (int)fminf(fmaxf(rintf(v.x / s), -127.f), 127.f);
        int b1 = (int)fminf(fmaxf(rintf(v.y / s), -127.f), 127.f);
        int b2 = (int)fminf(fmaxf(rintf(v.z / s), -127.f), 127.f);
        int b3 = (int)fminf(fmaxf(rintf(v.w / s), -127.f), 127.f);
        unsigned int packed = (b0 & 255) | ((b1 & 255) << 8) | ((b2 & 255) << 16) | ((b3 & 255) << 24);
        *(unsigned int*)(out + gt_addr(row, c * 4, cols)) = packed;
    }
}

// ---------------- int8 GEMM on tiled A/B: C[m,n] = sa[m]*sb[n]*idot ----------------
__global__ __launch_bounds__(256) void gemm_i8_k(const signed char* __restrict__ A,
        const float* __restrict__ sa, const signed char* __restrict__ B,
        const float* __restrict__ sb, float* __restrict__ C, int M, int N, int K) {
    __shared__ __align__(16) signed char lsA[8192];
    __shared__ __align__(16) signed char lsB[8192];
    int tid = threadIdx.x;
    int w = tid >> 6, l = tid & 63;
    int wr = w >> 1, wc = w & 1;
    int lrow = l & 15;
    int m0 = blockIdx.y * 128, n0 = blockIdx.x * 128;
    int kb6 = K >> 6;
    v4i acc[4][4];
#pragma unroll
    for (int i = 0; i < 4; ++i)
#pragma unroll
        for (int j = 0; j < 4; ++j) acc[i][j] = (v4i){0, 0, 0, 0};

    for (int k0 = 0; k0 < K; k0 += 64) {
        __syncthreads();
#pragma unroll
        for (int a = 0; a < 2; ++a) {
            int f = a * 4 + w;
            ASYNC16(A + (((size_t)(((m0 >> 4) + f) * kb6 + (k0 >> 6))) << 10) + l * 16,
                    lsA + f * 1024);
            ASYNC16(B + (((size_t)(((n0 >> 4) + f) * kb6 + (k0 >> 6))) << 10) + l * 16,
                    lsB + f * 1024);
        }
        __syncthreads();
        v4i af[4], bf[4];
#pragma unroll
        for (int i = 0; i < 4; ++i) af[i] = *(const v4i*)(lsA + (wr * 4 + i) * 1024 + l * 16);
#pragma unroll
        for (int j = 0; j < 4; ++j) bf[j] = *(const v4i*)(lsB + (wc * 4 + j) * 1024 + l * 16);
#pragma unroll
        for (int i = 0; i < 4; ++i)
#pragma unroll
            for (int j = 0; j < 4; ++j)
                acc[i][j] = __builtin_amdgcn_mfma_i32_16x16x64_i8(af[i], bf[j], acc[i][j], 0, 0, 0);
    }
    int r0 = m0 + wr * 64, c0 = n0 + wc * 64;
    int lg = l >> 4;
    float sbv[4];
#pragma unroll
    for (int j = 0; j < 4; ++j) sbv[j] = sb[c0 + j * 16 + lrow];
#pragma unroll
    for (int i = 0; i < 4; ++i) {
        float4 s4 = *(const float4*)(sa + r0 + i * 16 + lg * 4);
        float sav[4] = {s4.x, s4.y, s4.z, s4.w};
#pragma unroll
        for (int j = 0; j < 4; ++j) {
#pragma unroll
            for (int reg = 0; reg < 4; ++reg) {
                int r = r0 + i * 16 + lg * 4 + reg;
                C[(size_t)r * N + c0 + j * 16 + lrow] = (float)acc[i][j][reg] * (sav[reg] * sbv[j]);
            }
        }
    }
}

// ---------------- rope cos/sin table ----------------
__global__ void rope_tab_k(const int* __restrict__ pos_ids,
                           float* __restrict__ ct, float* __restrict__ st) {
    int t = blockIdx.x;
    int fi = threadIdx.x; // 64
    float pw = (float)pow(1.0e6, (double)fi / 64.0);
    float inv = 1.0f / pw;
    float fr = (float)pos_ids[t] * inv;
    float sn, c;
    sincosf(fr, &sn, &c);
    ct[t * 64 + fi] = c;
    st[t * 64 + fi] = sn;
}

// ---------------- rmsnorm + rope; q/k -> TILED int8 + scale, v -> fp32 ----------------
__global__ __launch_bounds__(128) void qkv_post_k(const float* __restrict__ q_lin,
        const float* __restrict__ k_lin, const float* __restrict__ v_lin,
        const float* __restrict__ qw, const float* __restrict__ kw,
        const float* __restrict__ ct, const float* __restrict__ st,
        signed char* __restrict__ q_i8, float* __restrict__ sq,
        signed char* __restrict__ k_i8, float* __restrict__ sk,
        float* __restrict__ v_dq) {
    int t = blockIdx.x;
    int hh = blockIdx.y;
    int d = threadIdx.x;
    __shared__ float xs[HDIM];
    __shared__ float red[2];
    float x;
    if (hh < NH)            x = q_lin[(size_t)t * DMODEL + hh * HDIM + d];
    else if (hh < NH + NKV) x = k_lin[(size_t)t * (NKV * HDIM) + (hh - NH) * HDIM + d];
    else                    x = v_lin[(size_t)t * (NKV * HDIM) + (hh - NH - NKV) * HDIM + d];

    if (hh < NH + NKV) {
        float sqv = x * x;
#pragma unroll
        for (int m = 32; m; m >>= 1) sqv += __shfl_xor(sqv, m);
        if ((d & 63) == 0) red[d >> 6] = sqv;
        __syncthreads();
        float mv = (red[0] + red[1]) / 128.0f;
        float rs = 1.0f / sqrtf(mv + 1e-6f);
        x = (x * rs) * ((hh < NH) ? qw[d] : kw[d]);
        xs[d] = x;
        __syncthreads();
        float other = (d < 64) ? xs[d + 64] : xs[d - 64];
        int fi = d & 63;
        float c = ct[t * 64 + fi];
        float sn = st[t * 64 + fi];
        x = (d < 64) ? (x * c - other * sn) : (x * c + other * sn);
        __syncthreads();
    }
    float amax = fabsf(x);
#pragma unroll
    for (int m = 32; m; m >>= 1) amax = fmaxf(amax, __shfl_xor(amax, m));
    if ((d & 63) == 0) red[d >> 6] = amax;
    __syncthreads();
    float s = fmaxf(fmaxf(red[0], red[1]) / 127.0f, 1e-8f);
    float qf = fminf(fmaxf(rintf(x / s), -127.f), 127.f);
    // tiled address within one head's [SEQ][128] i8 panel
    size_t ta = (size_t)(((t >> 4) * 2 + (d >> 6)) << 10)
              + (size_t)((((d >> 4) & 3) << 8) + ((t & 15) << 4) + (d & 15));
    if (hh < NH) {
        q_i8[(size_t)hh * (SEQ * 128) + ta] = (signed char)(int)qf;
        if (d == 0) sq[hh * SEQ + t] = s;
    } else if (hh < NH + NKV) {
        k_i8[(size_t)(hh - NH) * (SEQ * 128) + ta] = (signed char)(int)qf;
        if (d == 0) sk[(hh - NH) * SEQ + t] = s;
    } else {
        v_dq[(size_t)(hh - NH - NKV) * (SEQ * HDIM) + (size_t)t * HDIM + d] = qf * s;
    }
}

// ---------------- bf16 helpers ----------------
__device__ __forceinline__ unsigned int f2bf(float x) {
    unsigned int u = __float_as_uint(x);
    return (u + 0x7fffu + ((u >> 16) & 1u)) >> 16;
}
__device__ __forceinline__ float bf2f(unsigned int h) {
    return __uint_as_float(h << 16);
}

// ---------------- V transpose + bf16 split into MFMA-fragment-tiled vtT ----------------
// vtT halfword layout per (kv, sp): [kb][ (d>>4)*2 + ((t>>5)&1) ][ lane=(d&15)+16*((t>>3)&3) ][ t&7 ]
__global__ __launch_bounds__(256) void vt_split_k(const float* __restrict__ v_dq,
        unsigned short* __restrict__ vtT) {
    int kv = blockIdx.y, kb = blockIdx.x;
    int t0 = kb * 64;
    __shared__ float tile[64][132];
    int tid = threadIdx.x;
    const float* src = v_dq + ((size_t)kv * SEQ + t0) * HDIM;
#pragma unroll
    for (int i = 0; i < 8; ++i) {
        int f4 = i * 256 + tid;
        int r = f4 >> 5, c = (f4 & 31) << 2;
        float4 v = *(const float4*)(src + r * HDIM + c);
        tile[r][c] = v.x; tile[r][c + 1] = v.y; tile[r][c + 2] = v.z; tile[r][c + 3] = v.w;
    }
    __syncthreads();
    int d = tid >> 1, th = (tid & 1) * 32;
    size_t base_hi = (size_t)(kv * 2 + 0) * (SEQ * 128);
    size_t base_lo = (size_t)(kv * 2 + 1) * (SEQ * 128);
#pragma unroll
    for (int j = 0; j < 32; j += 2) {
        int tl = th + j;
        float a = tile[tl][d], b = tile[tl + 1][d];
        unsigned int ah = f2bf(a), bh = f2bf(b);
        unsigned int al = f2bf(a - bf2f(ah)), bl = f2bf(b - bf2f(bh));
        int off = kb * 8192 + ((d >> 4) * 2 + ((tl >> 5) & 1)) * 512
                + (((d & 15) + (((tl >> 3) & 3) << 4)) << 3) + (tl & 7);
        *(unsigned int*)(vtT + base_hi + off) = ah | (bh << 16);
        *(unsigned int*)(vtT + base_lo + off) = al | (bl << 16);
    }
}

// ---------------- attention pass 1 (split-K): partial (m, Z) per row ----------------
__global__ __launch_bounds__(256, 4) void attn_p1_k(const signed char* __restrict__ q_i8,
        const float* __restrict__ sq, const signed char* __restrict__ k_i8,
        const float* __restrict__ sk, float* __restrict__ mz) {
    int bx = blockIdx.x, h = blockIdx.y, kvh = h >> 1;
    int qb = bx >> 2, c = bx & 3;
    int nch = (qb + 8) >> 3;
    if (c >= nch) return;
    int q0 = qb * 64;
    int kb0 = c * 8, kb1 = min((c + 1) * 8, qb + 1);
    int tid = threadIdx.x, w = tid >> 6, l = tid & 63;
    int lrow = l & 15, lg = l >> 4;

    const signed char* qt = q_i8 + (size_t)h * (SEQ * 128)
                          + ((size_t)((((q0 >> 4) + w) * 2)) << 10) + l * 16;
    v4i qf0 = *(const v4i*)(qt);
    v4i qf1 = *(const v4i*)(qt + 1024);
    float4 s4 = *(const float4*)(sq + (size_t)h * SEQ + q0 + w * 16 + lg * 4);
    float sqr[4] = {s4.x, s4.y, s4.z, s4.w};
    const signed char* kbase = k_i8 + (size_t)kvh * (SEQ * 128);
    const float* skb = sk + (size_t)kvh * SEQ;

    float m_l[4], z_l[4];
#pragma unroll
    for (int r = 0; r < 4; ++r) { m_l[r] = -1e30f; z_l[r] = 0.f; }

    for (int kb = kb0; kb < kb1; ++kb) {
        int k0 = kb * 64;
        v4i ka[8];
#pragma unroll
        for (int f = 0; f < 8; ++f)
            ka[f] = *(const v4i*)(kbase + ((size_t)((k0 >> 4) * 2 + f) << 10) + l * 16);
        float skc[4];
#pragma unroll
        for (int j = 0; j < 4; ++j) skc[j] = skb[k0 + j * 16 + lrow];
        v4i sci[4];
#pragma unroll
        for (int j = 0; j < 4; ++j) {
            v4i z = {0, 0, 0, 0};
            v4i t0 = __builtin_amdgcn_mfma_i32_16x16x64_i8(qf0, ka[j * 2], z, 0, 0, 0);
            sci[j] = __builtin_amdgcn_mfma_i32_16x16x64_i8(qf1, ka[j * 2 + 1], t0, 0, 0, 0);
        }
#pragma unroll
        for (int reg = 0; reg < 4; ++reg) {
            int r = q0 + w * 16 + lg * 4 + reg;
            float s[4];
#pragma unroll
            for (int j = 0; j < 4; ++j) {
                float sv = ((float)sci[j][reg] * (sqr[reg] * skc[j])) * SM_SCALE;
                s[j] = (k0 + j * 16 + lrow <= r) ? sv : -1e30f;
            }
            float mt = fmaxf(fmaxf(s[0], s[1]), fmaxf(s[2], s[3]));
            float mn = fmaxf(m_l[reg], mt);
            float zt = 0.f;
#pragma unroll
            for (int j = 0; j < 4; ++j)
                zt += (s[j] > -5e29f) ? __expf(s[j] - mn) : 0.f;
            z_l[reg] = z_l[reg] * __expf(m_l[reg] - mn) + zt;
            m_l[reg] = mn;
        }
    }
#pragma unroll
    for (int reg = 0; reg < 4; ++reg) {
#pragma unroll
        for (int mask = 1; mask <= 8; mask <<= 1) {
            float om = __shfl_xor(m_l[reg], mask);
            float oz = __shfl_xor(z_l[reg], mask);
            float mn = fmaxf(m_l[reg], om);
            z_l[reg] = z_l[reg] * __expf(m_l[reg] - mn) + oz * __expf(om - mn);
            m_l[reg] = mn;
        }
    }
    if (lrow == 0) {
        size_t base = ((size_t)(h * 32 + qb) * 4 + c) * 128;
#pragma unroll
        for (int reg = 0; reg < 4; ++reg) {
            *(float2*)&mz[base + (w * 16 + lg * 4 + reg) * 2] =
                make_float2(m_l[reg], z_l[reg]);
        }
    }
}

// ---------------- attention pass 2 (split-K PV), fully coalesced ----------------
__global__ __launch_bounds__(256, 3) void attn_p2_k(const signed char* __restrict__ q_i8,
        const float* __restrict__ sq, const signed char* __restrict__ k_i8,
        const float* __restrict__ sk, const unsigned short* __restrict__ vtT,
        const float* __restrict__ mz, float* __restrict__ attn2, float* __restrict__ pp) {
    __shared__ __align__(16) unsigned short vlds[16384]; // 32 KB single buffer
    __shared__ __align__(16) unsigned short plds[4096];  // 8 KB wave-private
    int bx = blockIdx.x, h = blockIdx.y, kvh = h >> 1;
    int qb = 31 - (bx >> 1), c = bx & 1;
    int nch2 = (qb >= 16) ? 2 : 1;
    if (c >= nch2) return;
    int q0 = qb * 64;
    int kb0 = c * 16, kb1 = min((c + 1) * 16, qb + 1);
    int tid = threadIdx.x, w = tid >> 6, l = tid & 63;
    int lrow = l & 15, lg = l >> 4;

    const signed char* qt = q_i8 + (size_t)h * (SEQ * 128)
                          + ((size_t)((((q0 >> 4) + w) * 2)) << 10) + l * 16;
    v4i qf0 = *(const v4i*)(qt);
    v4i qf1 = *(const v4i*)(qt + 1024);
    float4 s4 = *(const float4*)(sq + (size_t)h * SEQ + q0 + w * 16 + lg * 4);
    float sqr[4] = {s4.x, s4.y, s4.z, s4.w};

    int nch1 = (qb + 8) >> 3;
    float m_fin[4], spv[4];
#pragma unroll
    for (int reg = 0; reg < 4; ++reg) {
        int r = w * 16 + lg * 4 + reg;
        float M = -1e30f, Z = 0.f;
        for (int c1 = 0; c1 < nch1; ++c1) {
            float2 p = *(const float2*)&mz[((size_t)(h * 32 + qb) * 4 + c1) * 128 + r * 2];
            float mn = fmaxf(M, p.x);
            Z = Z * __expf(M - mn) + p.y * __expf(p.x - mn);
            M = mn;
        }
        m_fin[reg] = M;
        float zinv = 1.0f / Z;
        spv[reg] = fmaxf(zinv / 127.0f, 1e-8f);
    }

    const signed char* kbase = k_i8 + (size_t)kvh * (SEQ * 128);
    const float* skb = sk + (size_t)kvh * SEQ;
    const unsigned short* vt_h = vtT + (size_t)(kvh * 2 + 0) * (SEQ * 128);
    const unsigned short* vt_l = vtT + (size_t)(kvh * 2 + 1) * (SEQ * 128);

    v4i ka[8], kn[8];
    float skc[4], skn[4];
    auto loadK = [&](v4i* dst, float* sdst, int k0) {
#pragma unroll
        for (int f = 0; f < 8; ++f)
            dst[f] = *(const v4i*)(kbase + ((size_t)((k0 >> 4) * 2 + f) << 10) + l * 16);
#pragma unroll
        for (int j = 0; j < 4; ++j) sdst[j] = skb[k0 + j * 16 + lrow];
    };
    auto issueV = [&](int kb) {
#pragma unroll
        for (int a = 0; a < 8; ++a) {
            int fv = a * 4 + w;
            int sp_ = fv >> 4, fr = fv & 15;
            const unsigned short* vsrc = (sp_ ? vt_l : vt_h) + kb * 8192 + fr * 512 + l * 8;
            ASYNC16(vsrc, vlds + fv * 512);
        }
    };

    v4f acco[8];
#pragma unroll
    for (int jd = 0; jd < 8; ++jd) acco[jd] = (v4f){0.f, 0.f, 0.f, 0.f};

    loadK(ka, skc, kb0 * 64);
    for (int kb = kb0; kb < kb1; ++kb) {
        int k0 = kb * 64;
        issueV(kb);                              // V-buf free (barrier at end of prev iter)
        if (kb + 1 < kb1) loadK(kn, skn, (kb + 1) * 64);
        v4i sci[4];
#pragma unroll
        for (int j = 0; j < 4; ++j) {
            v4i z = {0, 0, 0, 0};
            v4i t0 = __builtin_amdgcn_mfma_i32_16x16x64_i8(qf0, ka[j * 2], z, 0, 0, 0);
            sci[j] = __builtin_amdgcn_mfma_i32_16x16x64_i8(qf1, ka[j * 2 + 1], t0, 0, 0, 0);
        }
#pragma unroll
        for (int reg = 0; reg < 4; ++reg) {
            int rq = lg * 4 + reg;
            int r = q0 + w * 16 + rq;
#pragma unroll
            for (int j = 0; j < 4; ++j) {
                int cc = j * 16 + lrow;
                float pd = 0.f;
                if (k0 + cc <= r) {
                    float sv = ((float)sci[j][reg] * (sqr[reg] * skc[j])) * SM_SCALE;
                    pd = fminf(rintf(127.0f * __expf(sv - m_fin[reg])), 127.f);
                }
                plds[(w * 2 + (cc >> 5)) * 512 + (rq + 16 * ((cc >> 3) & 3)) * 8 + (cc & 7)] =
                    (unsigned short)(__float_as_uint(pd) >> 16);
            }
        }
        v8bf pf0 = *(const v8bf*)(plds + (w * 2 + 0) * 512 + l * 8);
        v8bf pf1 = *(const v8bf*)(plds + (w * 2 + 1) * 512 + l * 8);
        asm volatile("s_waitcnt vmcnt(0)" ::: "memory");
        __syncthreads();                         // vlds fully written, visible to all waves
#pragma unroll
        for (int jd = 0; jd < 8; ++jd) {
            v8bf vh0 = *(const v8bf*)(vlds + (jd * 2 + 0) * 512 + l * 8);
            v8bf vh1 = *(const v8bf*)(vlds + (jd * 2 + 1) * 512 + l * 8);
            v8bf vl0 = *(const v8bf*)(vlds + (16 + jd * 2 + 0) * 512 + l * 8);
            v8bf vl1 = *(const v8bf*)(vlds + (16 + jd * 2 + 1) * 512 + l * 8);
            v4f t = acco[jd];
            t = __builtin_amdgcn_mfma_f32_16x16x32_bf16(pf0, vh0, t, 0, 0, 0);
            t = __builtin_amdgcn_mfma_f32_16x16x32_bf16(pf1, vh1, t, 0, 0, 0);
            t = __builtin_amdgcn_mfma_f32_16x16x32_bf16(pf0, vl0, t, 0, 0, 0);
            t = __builtin_amdgcn_mfma_f32_16x16x32_bf16(pf1, vl1, t, 0, 0, 0);
            acco[jd] = t;
        }
        __syncthreads();                         // PV reads done before next issueV overwrite
        if (kb + 1 < kb1) {
#pragma unroll
            for (int f = 0; f < 8; ++f) ka[f] = kn[f];
#pragma unroll
            for (int j = 0; j < 4; ++j) skc[j] = skn[j];
        }
    }
    if (c == 0) {
#pragma unroll
        for (int jd = 0; jd < 8; ++jd)
#pragma unroll
            for (int reg = 0; reg < 4; ++reg) {
                int r = q0 + w * 16 + lg * 4 + reg;
                attn2[(size_t)r * DMODEL + h * HDIM + jd * 16 + lrow] = acco[jd][reg] * spv[reg];
            }
    } else {
#pragma unroll
        for (int jd = 0; jd < 8; ++jd)
#pragma unroll
            for (int reg = 0; reg < 4; ++reg) {
                int rr = w * 16 + lg * 4 + reg;
                pp[(((size_t)h * 16 + (qb - 16)) * 64 + rr) * 128 + jd * 16 + lrow] =
                    acco[jd][reg] * spv[reg];
            }
    }
}

// ---------------- reduce: attn2 += chunk-1 partials (tiles qb>=16) ----------------
__global__ __launch_bounds__(256) void attn_red_k(float* __restrict__ attn2,
        const float* __restrict__ pp) {
    int t16 = blockIdx.x, h = blockIdx.y;
    int qb = t16 + 16;
    int tid = threadIdx.x;
    for (int e = tid; e < 2048; e += 256) {
        int i = (e * 4) >> 7, j = (e * 4) & 127;
        float4 p = *(const float4*)&pp[(((size_t)h * 16 + t16) * 64 + i) * 128 + j];
        float* d = &attn2[(size_t)(qb * 64 + i) * DMODEL + h * HDIM + j];
        float4 dv = *(float4*)d;
        dv.x += p.x; dv.y += p.y; dv.z += p.z; dv.w += p.w;
        *(float4*)d = dv;
    }
}

extern "C" void kernel_launch(void* const* d_in, const int* in_sizes, int n_in,
                              void* d_out, int out_size, void* d_ws, size_t ws_size,
                              hipStream_t stream) {
    (void)in_sizes; (void)n_in; (void)out_size; (void)ws_size;
    const float* hidden = (const float*)d_in[0];
    const float* Wq = (const float*)d_in[1];
    const float* Wk = (const float*)d_in[2];
    const float* Wv = (const float*)d_in[3];
    const float* Wo = (const float*)d_in[4];
    const float* qw = (const float*)d_in[5];
    const float* kw = (const float*)d_in[6];
    const int* pos = (const int*)d_in[7];
    float* out = (float*)d_out;
    char* ws = (char*)d_ws;

    const size_t MB = 1024 * 1024;
    signed char* x_i8  = (signed char*)(ws);            // 4 MB (tiled)
    signed char* wq_i8 = (signed char*)(ws + 4 * MB);   // 4 MB (tiled)
    signed char* wk_i8 = (signed char*)(ws + 8 * MB);   // 2 MB (tiled)
    signed char* wv_i8 = (signed char*)(ws + 10 * MB);  // 2 MB (tiled)
    signed char* wo_i8 = (signed char*)(ws + 12 * MB);  // 4 MB (tiled)
    signed char* q_i8  = (signed char*)(ws + 16 * MB);  // 4 MB (attn-tiled)
    signed char* k_i8  = (signed char*)(ws + 20 * MB);  // 2 MB (attn-tiled)
    float* sx  = (float*)(ws + 22 * MB);
    float* swq = sx + 2048;
    float* swk = swq + 2048;
    float* swv = swk + 1024;
    float* swo = swv + 1024;
    float* sq  = swo + 2048;                            // 16*2048
    float* sk  = sq + NH * SEQ;                         // 8*2048
    float* sa  = sk + NKV * SEQ;                        // 2048
    float* ct  = (float*)(ws + 22 * MB + 512 * 1024);   // 512 KB
    float* st  = (float*)(ws + 22 * MB + 1024 * 1024);  // 512 KB
    float* q_lin = (float*)(ws + 24 * MB);              // 16 MB -> attn2
    float* k_lin = (float*)(ws + 40 * MB);              // 8 MB  -> pp
    float* v_lin = (float*)(ws + 48 * MB);              // 8 MB  -> vtT
    unsigned short* vtT = (unsigned short*)(ws + 48 * MB); // 8 MB (aliases dead v_lin)
    float* v_dq = (float*)(ws + 56 * MB);               // 8 MB  -> mz after vt_split
    float* mz   = (float*)(ws + 56 * MB);               // 1 MB (aliases dead v_dq)
    float* pp   = (float*)(ws + 40 * MB);               // 8 MB (aliases dead k_lin)
    float* attn2 = q_lin;
    signed char* a_i8 = x_i8;

    rope_tab_k<<<2048, 64, 0, stream>>>(pos, ct, st);
    row_quant_k<<<2048, 256, 0, stream>>>(hidden, x_i8, sx, 2048);
    row_quant_k<<<2048, 256, 0, stream>>>(Wq, wq_i8, swq, 2048);
    row_quant_k<<<1024, 256, 0, stream>>>(Wk, wk_i8, swk, 2048);
    row_quant_k<<<1024, 256, 0, stream>>>(Wv, wv_i8, swv, 2048);
    row_quant_k<<<2048, 256, 0, stream>>>(Wo, wo_i8, swo, 2048);

    gemm_i8_k<<<dim3(16, 16), 256, 0, stream>>>(x_i8, sx, wq_i8, swq, q_lin, 2048, 2048, 2048);
    gemm_i8_k<<<dim3(8, 16), 256, 0, stream>>>(x_i8, sx, wk_i8, swk, k_lin, 2048, 1024, 2048);
    gemm_i8_k<<<dim3(8, 16), 256, 0, stream>>>(x_i8, sx, wv_i8, swv, v_lin, 2048, 1024, 2048);

    qkv_post_k<<<dim3(2048, 32), 128, 0, stream>>>(q_lin, k_lin, v_lin, qw, kw, ct, st,
                                                   q_i8, sq, k_i8, sk, v_dq);
    vt_split_k<<<dim3(32, 8), 256, 0, stream>>>(v_dq, vtT);

    attn_p1_k<<<dim3(128, 16), 256, 0, stream>>>(q_i8, sq, k_i8, sk, mz);
    attn_p2_k<<<dim3(64, 16), 256, 0, stream>>>(q_i8, sq, k_i8, sk, vtT, mz, attn2, pp);
    attn_red_k<<<dim3(16, 16), 256, 0, stream>>>(attn2, pp);

    row_quant_k<<<2048, 256, 0, stream>>>(attn2, a_i8, sa, 2048);
    gemm_i8_k<<<dim3(16, 16), 256, 0, stream>>>(a_i8, sa, wo_i8, swo, out, 2048, 2048, 2048);
}

// Round 6
// 371.312 us; speedup vs baseline: 1.2755x; 1.2755x over previous
//
#include <hip/hip_runtime.h>
#include <math.h>

#define NH 16
#define NKV 8
#define HDIM 128
#define SEQ 2048
#define DMODEL 2048

typedef int   v4i __attribute__((ext_vector_type(4)));
typedef float v4f __attribute__((ext_vector_type(4)));
typedef __bf16 v8bf __attribute__((ext_vector_type(8)));

static constexpr float SM_SCALE = 0.08838834764831843f; // 128**-0.5

#define GLOBP(p) (__attribute__((address_space(1))) void*)(p)
#define LDSP(p)  (__attribute__((address_space(3))) void*)(p)
#define ASYNC16(g, l) __builtin_amdgcn_global_load_lds(GLOBP(g), LDSP(l), 16, 0, 0)

// Fragment-tiled i8 layout for X[R][K] (R%16==0, K%64==0):
// frag (r>>4, k>>6) is 1024B; within: byte = ((k>>4)&3)*256 + (r&15)*16 + (k&15).
// A wave fragment read/ASYNC16 is then base + lane*16 -> fully coalesced 1KB.

// ---------------- per-row symmetric int8 quant, 16 rows/block, coalesced tiled writes ----
__global__ __launch_bounds__(256) void row_quant_k(const float* __restrict__ in,
        signed char* __restrict__ out, float* __restrict__ scale, int cols) {
    int row0 = blockIdx.x * 16;
    int tid = threadIdx.x;
    __shared__ float srow[16];
    // phase A: per-row amax (16 threads per row, coalesced 64B per 16-lane group)
    int r = tid >> 4, l16 = tid & 15;
    const float4* x4 = (const float4*)(in + (size_t)(row0 + r) * cols);
    int n4 = cols >> 2;
    float amax = 0.f;
    for (int c4 = l16; c4 < n4; c4 += 16) {
        float4 v = x4[c4];
        amax = fmaxf(amax, fmaxf(fmaxf(fabsf(v.x), fabsf(v.y)),
                                 fmaxf(fabsf(v.z), fabsf(v.w))));
    }
#pragma unroll
    for (int m = 1; m <= 8; m <<= 1) amax = fmaxf(amax, __shfl_xor(amax, m));
    if (l16 == 0) {
        float s = fmaxf(amax / 127.0f, 1e-8f);
        srow[r] = s;
        scale[row0 + r] = s;
    }
    __syncthreads();
    // phase B: quantize + contiguous 16B tiled stores
    int nchunk = cols >> 4;                    // 16B output chunks per row * 16 rows / ...
    int total = nchunk * 16;                   // total 16B chunks for the 16-row panel
    size_t obase = ((size_t)(row0 >> 4) * (cols >> 6)) << 10;
    for (int idx = tid; idx < total; idx += 256) {
        int f = idx >> 6, q = (idx >> 4) & 3, rr = idx & 15;
        const float* src = in + (size_t)(row0 + rr) * cols + f * 64 + q * 16;
        float s = srow[rr];
        unsigned int wds[4];
#pragma unroll
        for (int g = 0; g < 4; ++g) {
            float4 v = *(const float4*)(src + g * 4);
            int b0 = (int)fminf(fmaxf(rintf(v.x / s), -127.f), 127.f);
            int b1 = (int)fminf(fmaxf(rintf(v.y / s), -127.f), 127.f);
            int b2 = (int)fminf(fmaxf(rintf(v.z / s), -127.f), 127.f);
            int b3 = (int)fminf(fmaxf(rintf(v.w / s), -127.f), 127.f);
            wds[g] = (b0 & 255) | ((b1 & 255) << 8) | ((b2 & 255) << 16) | ((b3 & 255) << 24);
        }
        *(uint4*)(out + obase + (size_t)idx * 16) =
            make_uint4(wds[0], wds[1], wds[2], wds[3]);
    }
}

// ---------------- int8 GEMM on tiled A/B: C[m,n] = sa[m]*sb[n]*idot ----------------
__global__ __launch_bounds__(256) void gemm_i8_k(const signed char* __restrict__ A,
        const float* __restrict__ sa, const signed char* __restrict__ B,
        const float* __restrict__ sb, float* __restrict__ C, int M, int N, int K) {
    __shared__ __align__(16) signed char lsA[8192];
    __shared__ __align__(16) signed char lsB[8192];
    int tid = threadIdx.x;
    int w = tid >> 6, l = tid & 63;
    int wr = w >> 1, wc = w & 1;
    int lrow = l & 15;
    int m0 = blockIdx.y * 128, n0 = blockIdx.x * 128;
    int kb6 = K >> 6;
    v4i acc[4][4];
#pragma unroll
    for (int i = 0; i < 4; ++i)
#pragma unroll
        for (int j = 0; j < 4; ++j) acc[i][j] = (v4i){0, 0, 0, 0};

    for (int k0 = 0; k0 < K; k0 += 64) {
        __syncthreads();
#pragma unroll
        for (int a = 0; a < 2; ++a) {
            int f = a * 4 + w;
            ASYNC16(A + (((size_t)(((m0 >> 4) + f) * kb6 + (k0 >> 6))) << 10) + l * 16,
                    lsA + f * 1024);
            ASYNC16(B + (((size_t)(((n0 >> 4) + f) * kb6 + (k0 >> 6))) << 10) + l * 16,
                    lsB + f * 1024);
        }
        __syncthreads();
        v4i af[4], bf[4];
#pragma unroll
        for (int i = 0; i < 4; ++i) af[i] = *(const v4i*)(lsA + (wr * 4 + i) * 1024 + l * 16);
#pragma unroll
        for (int j = 0; j < 4; ++j) bf[j] = *(const v4i*)(lsB + (wc * 4 + j) * 1024 + l * 16);
#pragma unroll
        for (int i = 0; i < 4; ++i)
#pragma unroll
            for (int j = 0; j < 4; ++j)
                acc[i][j] = __builtin_amdgcn_mfma_i32_16x16x64_i8(af[i], bf[j], acc[i][j], 0, 0, 0);
    }
    int r0 = m0 + wr * 64, c0 = n0 + wc * 64;
    int lg = l >> 4;
    float sbv[4];
#pragma unroll
    for (int j = 0; j < 4; ++j) sbv[j] = sb[c0 + j * 16 + lrow];
#pragma unroll
    for (int i = 0; i < 4; ++i) {
        float4 s4 = *(const float4*)(sa + r0 + i * 16 + lg * 4);
        float sav[4] = {s4.x, s4.y, s4.z, s4.w};
#pragma unroll
        for (int j = 0; j < 4; ++j) {
#pragma unroll
            for (int reg = 0; reg < 4; ++reg) {
                int rr = r0 + i * 16 + lg * 4 + reg;
                C[(size_t)rr * N + c0 + j * 16 + lrow] = (float)acc[i][j][reg] * (sav[reg] * sbv[j]);
            }
        }
    }
}

// ---------------- rope cos/sin table ----------------
__global__ void rope_tab_k(const int* __restrict__ pos_ids,
                           float* __restrict__ ct, float* __restrict__ st) {
    int t = blockIdx.x;
    int fi = threadIdx.x; // 64
    float pw = (float)pow(1.0e6, (double)fi / 64.0);
    float inv = 1.0f / pw;
    float fr = (float)pos_ids[t] * inv;
    float sn, c;
    sincosf(fr, &sn, &c);
    ct[t * 64 + fi] = c;
    st[t * 64 + fi] = sn;
}

// ---------------- rmsnorm + rope; q/k -> TILED int8 + scale, v -> fp32 ----------------
__global__ __launch_bounds__(128) void qkv_post_k(const float* __restrict__ q_lin,
        const float* __restrict__ k_lin, const float* __restrict__ v_lin,
        const float* __restrict__ qw, const float* __restrict__ kw,
        const float* __restrict__ ct, const float* __restrict__ st,
        signed char* __restrict__ q_i8, float* __restrict__ sq,
        signed char* __restrict__ k_i8, float* __restrict__ sk,
        float* __restrict__ v_dq) {
    int t = blockIdx.x;
    int hh = blockIdx.y;
    int d = threadIdx.x;
    __shared__ float xs[HDIM];
    __shared__ float red[2];
    float x;
    if (hh < NH)            x = q_lin[(size_t)t * DMODEL + hh * HDIM + d];
    else if (hh < NH + NKV) x = k_lin[(size_t)t * (NKV * HDIM) + (hh - NH) * HDIM + d];
    else                    x = v_lin[(size_t)t * (NKV * HDIM) + (hh - NH - NKV) * HDIM + d];

    if (hh < NH + NKV) {
        float sqv = x * x;
#pragma unroll
        for (int m = 32; m; m >>= 1) sqv += __shfl_xor(sqv, m);
        if ((d & 63) == 0) red[d >> 6] = sqv;
        __syncthreads();
        float mv = (red[0] + red[1]) / 128.0f;
        float rs = 1.0f / sqrtf(mv + 1e-6f);
        x = (x * rs) * ((hh < NH) ? qw[d] : kw[d]);
        xs[d] = x;
        __syncthreads();
        float other = (d < 64) ? xs[d + 64] : xs[d - 64];
        int fi = d & 63;
        float c = ct[t * 64 + fi];
        float sn = st[t * 64 + fi];
        x = (d < 64) ? (x * c - other * sn) : (x * c + other * sn);
        __syncthreads();
    }
    float amax = fabsf(x);
#pragma unroll
    for (int m = 32; m; m >>= 1) amax = fmaxf(amax, __shfl_xor(amax, m));
    if ((d & 63) == 0) red[d >> 6] = amax;
    __syncthreads();
    float s = fmaxf(fmaxf(red[0], red[1]) / 127.0f, 1e-8f);
    float qf = fminf(fmaxf(rintf(x / s), -127.f), 127.f);
    // tiled address within one head's [SEQ][128] i8 panel
    size_t ta = (size_t)(((t >> 4) * 2 + (d >> 6)) << 10)
              + (size_t)((((d >> 4) & 3) << 8) + ((t & 15) << 4) + (d & 15));
    if (hh < NH) {
        q_i8[(size_t)hh * (SEQ * 128) + ta] = (signed char)(int)qf;
        if (d == 0) sq[hh * SEQ + t] = s;
    } else if (hh < NH + NKV) {
        k_i8[(size_t)(hh - NH) * (SEQ * 128) + ta] = (signed char)(int)qf;
        if (d == 0) sk[(hh - NH) * SEQ + t] = s;
    } else {
        v_dq[(size_t)(hh - NH - NKV) * (SEQ * HDIM) + (size_t)t * HDIM + d] = qf * s;
    }
}

// ---------------- bf16 helpers ----------------
__device__ __forceinline__ unsigned int f2bf(float x) {
    unsigned int u = __float_as_uint(x);
    return (u + 0x7fffu + ((u >> 16) & 1u)) >> 16;
}
__device__ __forceinline__ float bf2f(unsigned int h) {
    return __uint_as_float(h << 16);
}

// ---------------- V transpose + bf16 split into MFMA-fragment-tiled vtT ----------------
__global__ __launch_bounds__(256) void vt_split_k(const float* __restrict__ v_dq,
        unsigned short* __restrict__ vtT) {
    int kv = blockIdx.y, kb = blockIdx.x;
    int t0 = kb * 64;
    __shared__ float tile[64][132];
    int tid = threadIdx.x;
    const float* src = v_dq + ((size_t)kv * SEQ + t0) * HDIM;
#pragma unroll
    for (int i = 0; i < 8; ++i) {
        int f4 = i * 256 + tid;
        int r = f4 >> 5, c = (f4 & 31) << 2;
        float4 v = *(const float4*)(src + r * HDIM + c);
        tile[r][c] = v.x; tile[r][c + 1] = v.y; tile[r][c + 2] = v.z; tile[r][c + 3] = v.w;
    }
    __syncthreads();
    int d = tid >> 1, th = (tid & 1) * 32;
    size_t base_hi = (size_t)(kv * 2 + 0) * (SEQ * 128);
    size_t base_lo = (size_t)(kv * 2 + 1) * (SEQ * 128);
#pragma unroll
    for (int j = 0; j < 32; j += 2) {
        int tl = th + j;
        float a = tile[tl][d], b = tile[tl + 1][d];
        unsigned int ah = f2bf(a), bh = f2bf(b);
        unsigned int al = f2bf(a - bf2f(ah)), bl = f2bf(b - bf2f(bh));
        int off = kb * 8192 + ((d >> 4) * 2 + ((tl >> 5) & 1)) * 512
                + (((d & 15) + (((tl >> 3) & 3) << 4)) << 3) + (tl & 7);
        *(unsigned int*)(vtT + base_hi + off) = ah | (bh << 16);
        *(unsigned int*)(vtT + base_lo + off) = al | (bl << 16);
    }
}

// ---------------- attention pass 1 (split-K): partial (m, Z) per row ----------------
__global__ __launch_bounds__(256, 4) void attn_p1_k(const signed char* __restrict__ q_i8,
        const float* __restrict__ sq, const signed char* __restrict__ k_i8,
        const float* __restrict__ sk, float* __restrict__ mz) {
    int bx = blockIdx.x, h = blockIdx.y, kvh = h >> 1;
    int qb = 31 - (bx >> 2), c = bx & 3;
    int nch = (qb + 8) >> 3;
    if (c >= nch) return;
    int q0 = qb * 64;
    int kb0 = c * 8, kb1 = min((c + 1) * 8, qb + 1);
    int tid = threadIdx.x, w = tid >> 6, l = tid & 63;
    int lrow = l & 15, lg = l >> 4;

    const signed char* qt = q_i8 + (size_t)h * (SEQ * 128)
                          + ((size_t)((((q0 >> 4) + w) * 2)) << 10) + l * 16;
    v4i qf0 = *(const v4i*)(qt);
    v4i qf1 = *(const v4i*)(qt + 1024);
    float4 s4 = *(const float4*)(sq + (size_t)h * SEQ + q0 + w * 16 + lg * 4);
    float sqr[4] = {s4.x, s4.y, s4.z, s4.w};
    const signed char* kbase = k_i8 + (size_t)kvh * (SEQ * 128);
    const float* skb = sk + (size_t)kvh * SEQ;

    float m_l[4], z_l[4];
#pragma unroll
    for (int r = 0; r < 4; ++r) { m_l[r] = -1e30f; z_l[r] = 0.f; }

    v4i ka[8], kn[8];
    float skc[4], skn[4];
    auto loadK = [&](v4i* dst, float* sdst, int k0) {
#pragma unroll
        for (int f = 0; f < 8; ++f)
            dst[f] = *(const v4i*)(kbase + ((size_t)((k0 >> 4) * 2 + f) << 10) + l * 16);
#pragma unroll
        for (int j = 0; j < 4; ++j) sdst[j] = skb[k0 + j * 16 + lrow];
    };

    loadK(ka, skc, kb0 * 64);
    for (int kb = kb0; kb < kb1; ++kb) {
        if (kb + 1 < kb1) loadK(kn, skn, (kb + 1) * 64);
        int k0 = kb * 64;
        v4i sci[4];
#pragma unroll
        for (int j = 0; j < 4; ++j) {
            v4i z = {0, 0, 0, 0};
            v4i t0 = __builtin_amdgcn_mfma_i32_16x16x64_i8(qf0, ka[j * 2], z, 0, 0, 0);
            sci[j] = __builtin_amdgcn_mfma_i32_16x16x64_i8(qf1, ka[j * 2 + 1], t0, 0, 0, 0);
        }
#pragma unroll
        for (int reg = 0; reg < 4; ++reg) {
            int r = q0 + w * 16 + lg * 4 + reg;
            float s[4];
#pragma unroll
            for (int j = 0; j < 4; ++j) {
                float sv = ((float)sci[j][reg] * (sqr[reg] * skc[j])) * SM_SCALE;
                s[j] = (k0 + j * 16 + lrow <= r) ? sv : -1e30f;
            }
            float mt = fmaxf(fmaxf(s[0], s[1]), fmaxf(s[2], s[3]));
            float mn = fmaxf(m_l[reg], mt);
            float zt = 0.f;
#pragma unroll
            for (int j = 0; j < 4; ++j)
                zt += (s[j] > -5e29f) ? __expf(s[j] - mn) : 0.f;
            z_l[reg] = z_l[reg] * __expf(m_l[reg] - mn) + zt;
            m_l[reg] = mn;
        }
        if (kb + 1 < kb1) {
#pragma unroll
            for (int f = 0; f < 8; ++f) ka[f] = kn[f];
#pragma unroll
            for (int j = 0; j < 4; ++j) skc[j] = skn[j];
        }
    }
#pragma unroll
    for (int reg = 0; reg < 4; ++reg) {
#pragma unroll
        for (int mask = 1; mask <= 8; mask <<= 1) {
            float om = __shfl_xor(m_l[reg], mask);
            float oz = __shfl_xor(z_l[reg], mask);
            float mn = fmaxf(m_l[reg], om);
            z_l[reg] = z_l[reg] * __expf(m_l[reg] - mn) + oz * __expf(om - mn);
            m_l[reg] = mn;
        }
    }
    if (lrow == 0) {
        size_t base = ((size_t)(h * 32 + qb) * 4 + c) * 128;
#pragma unroll
        for (int reg = 0; reg < 4; ++reg) {
            *(float2*)&mz[base + (w * 16 + lg * 4 + reg) * 2] =
                make_float2(m_l[reg], z_l[reg]);
        }
    }
}

// ---------------- attention pass 2 (split-K PV), tiled + double-buffered V ----------------
__global__ __launch_bounds__(256, 2) void attn_p2_k(const signed char* __restrict__ q_i8,
        const float* __restrict__ sq, const signed char* __restrict__ k_i8,
        const float* __restrict__ sk, const unsigned short* __restrict__ vtT,
        const float* __restrict__ mz, float* __restrict__ attn2, float* __restrict__ pp) {
    __shared__ __align__(16) unsigned short vlds[2][16384]; // 2 x 32 KB
    __shared__ __align__(16) unsigned short plds[4096];     // 8 KB wave-private
    int bx = blockIdx.x, h = blockIdx.y, kvh = h >> 1;
    int qb = 31 - (bx >> 1), c = bx & 1;
    int nch2 = (qb >= 16) ? 2 : 1;
    if (c >= nch2) return;
    int q0 = qb * 64;
    int kb0 = c * 16, kb1 = min((c + 1) * 16, qb + 1);
    int tid = threadIdx.x, w = tid >> 6, l = tid & 63;
    int lrow = l & 15, lg = l >> 4;

    const signed char* qt = q_i8 + (size_t)h * (SEQ * 128)
                          + ((size_t)((((q0 >> 4) + w) * 2)) << 10) + l * 16;
    v4i qf0 = *(const v4i*)(qt);
    v4i qf1 = *(const v4i*)(qt + 1024);
    float4 s4 = *(const float4*)(sq + (size_t)h * SEQ + q0 + w * 16 + lg * 4);
    float sqr[4] = {s4.x, s4.y, s4.z, s4.w};

    int nch1 = (qb + 8) >> 3;
    float m_fin[4], spv[4];
#pragma unroll
    for (int reg = 0; reg < 4; ++reg) {
        int r = w * 16 + lg * 4 + reg;
        float M = -1e30f, Z = 0.f;
        for (int c1 = 0; c1 < nch1; ++c1) {
            float2 p = *(const float2*)&mz[((size_t)(h * 32 + qb) * 4 + c1) * 128 + r * 2];
            float mn = fmaxf(M, p.x);
            Z = Z * __expf(M - mn) + p.y * __expf(p.x - mn);
            M = mn;
        }
        m_fin[reg] = M;
        float zinv = 1.0f / Z;
        spv[reg] = fmaxf(zinv / 127.0f, 1e-8f);
    }

    const signed char* kbase = k_i8 + (size_t)kvh * (SEQ * 128);
    const float* skb = sk + (size_t)kvh * SEQ;
    const unsigned short* vt_h = vtT + (size_t)(kvh * 2 + 0) * (SEQ * 128);
    const unsigned short* vt_l = vtT + (size_t)(kvh * 2 + 1) * (SEQ * 128);

    v4i ka[8], kn[8];
    float skc[4], skn[4];
    auto loadK = [&](v4i* dst, float* sdst, int k0) {
#pragma unroll
        for (int f = 0; f < 8; ++f)
            dst[f] = *(const v4i*)(kbase + ((size_t)((k0 >> 4) * 2 + f) << 10) + l * 16);
#pragma unroll
        for (int j = 0; j < 4; ++j) sdst[j] = skb[k0 + j * 16 + lrow];
    };
    auto issueV = [&](int kb) {
        unsigned short* vb = &vlds[kb & 1][0];
#pragma unroll
        for (int a = 0; a < 8; ++a) {
            int fv = a * 4 + w;
            int sp_ = fv >> 4, fr = fv & 15;
            const unsigned short* vsrc = (sp_ ? vt_l : vt_h) + kb * 8192 + fr * 512 + l * 8;
            ASYNC16(vsrc, vb + fv * 512);
        }
    };

    v4f acco[8];
#pragma unroll
    for (int jd = 0; jd < 8; ++jd) acco[jd] = (v4f){0.f, 0.f, 0.f, 0.f};

    loadK(ka, skc, kb0 * 64);
    issueV(kb0);
    asm volatile("s_waitcnt vmcnt(0)" ::: "memory");
    __syncthreads();
    for (int kb = kb0; kb < kb1; ++kb) {
        int k0 = kb * 64;
        // issue next tile's loads early: they complete under this tile's compute
        if (kb + 1 < kb1) {
            issueV(kb + 1);
            loadK(kn, skn, (kb + 1) * 64);
        }
        v4i sci[4];
#pragma unroll
        for (int j = 0; j < 4; ++j) {
            v4i z = {0, 0, 0, 0};
            v4i t0 = __builtin_amdgcn_mfma_i32_16x16x64_i8(qf0, ka[j * 2], z, 0, 0, 0);
            sci[j] = __builtin_amdgcn_mfma_i32_16x16x64_i8(qf1, ka[j * 2 + 1], t0, 0, 0, 0);
        }
#pragma unroll
        for (int reg = 0; reg < 4; ++reg) {
            int rq = lg * 4 + reg;
            int r = q0 + w * 16 + rq;
#pragma unroll
            for (int j = 0; j < 4; ++j) {
                int cc = j * 16 + lrow;
                float pd = 0.f;
                if (k0 + cc <= r) {
                    float sv = ((float)sci[j][reg] * (sqr[reg] * skc[j])) * SM_SCALE;
                    pd = fminf(rintf(127.0f * __expf(sv - m_fin[reg])), 127.f);
                }
                plds[(w * 2 + (cc >> 5)) * 512 + (rq + 16 * ((cc >> 3) & 3)) * 8 + (cc & 7)] =
                    (unsigned short)(__float_as_uint(pd) >> 16);
            }
        }
        // plds region is wave-private: same-wave LDS ordering is automatic
        v8bf pf0 = *(const v8bf*)(plds + (w * 2 + 0) * 512 + l * 8);
        v8bf pf1 = *(const v8bf*)(plds + (w * 2 + 1) * 512 + l * 8);
        const unsigned short* vb = &vlds[kb & 1][0];
#pragma unroll
        for (int jd = 0; jd < 8; ++jd) {
            v8bf vh0 = *(const v8bf*)(vb + (jd * 2 + 0) * 512 + l * 8);
            v8bf vh1 = *(const v8bf*)(vb + (jd * 2 + 1) * 512 + l * 8);
            v8bf vl0 = *(const v8bf*)(vb + (16 + jd * 2 + 0) * 512 + l * 8);
            v8bf vl1 = *(const v8bf*)(vb + (16 + jd * 2 + 1) * 512 + l * 8);
            v4f t = acco[jd];
            t = __builtin_amdgcn_mfma_f32_16x16x32_bf16(pf0, vh0, t, 0, 0, 0);
            t = __builtin_amdgcn_mfma_f32_16x16x32_bf16(pf1, vh1, t, 0, 0, 0);
            t = __builtin_amdgcn_mfma_f32_16x16x32_bf16(pf0, vl0, t, 0, 0, 0);
            t = __builtin_amdgcn_mfma_f32_16x16x32_bf16(pf1, vl1, t, 0, 0, 0);
            acco[jd] = t;
        }
        // drain next tile's ASYNC16 + K prefetch; barrier makes buffer swap safe
        asm volatile("s_waitcnt vmcnt(0)" ::: "memory");
        __syncthreads();
        if (kb + 1 < kb1) {
#pragma unroll
            for (int f = 0; f < 8; ++f) ka[f] = kn[f];
#pragma unroll
            for (int j = 0; j < 4; ++j) skc[j] = skn[j];
        }
    }
    if (c == 0) {
#pragma unroll
        for (int jd = 0; jd < 8; ++jd)
#pragma unroll
            for (int reg = 0; reg < 4; ++reg) {
                int r = q0 + w * 16 + lg * 4 + reg;
                attn2[(size_t)r * DMODEL + h * HDIM + jd * 16 + lrow] = acco[jd][reg] * spv[reg];
            }
    } else {
#pragma unroll
        for (int jd = 0; jd < 8; ++jd)
#pragma unroll
            for (int reg = 0; reg < 4; ++reg) {
                int rr = w * 16 + lg * 4 + reg;
                pp[(((size_t)h * 16 + (qb - 16)) * 64 + rr) * 128 + jd * 16 + lrow] =
                    acco[jd][reg] * spv[reg];
            }
    }
}

// ---------------- reduce: attn2 += chunk-1 partials (tiles qb>=16) ----------------
__global__ __launch_bounds__(256) void attn_red_k(float* __restrict__ attn2,
        const float* __restrict__ pp) {
    int t16 = blockIdx.x, h = blockIdx.y;
    int qb = t16 + 16;
    int tid = threadIdx.x;
    for (int e = tid; e < 2048; e += 256) {
        int i = (e * 4) >> 7, j = (e * 4) & 127;
        float4 p = *(const float4*)&pp[(((size_t)h * 16 + t16) * 64 + i) * 128 + j];
        float* d = &attn2[(size_t)(qb * 64 + i) * DMODEL + h * HDIM + j];
        float4 dv = *(float4*)d;
        dv.x += p.x; dv.y += p.y; dv.z += p.z; dv.w += p.w;
        *(float4*)d = dv;
    }
}

extern "C" void kernel_launch(void* const* d_in, const int* in_sizes, int n_in,
                              void* d_out, int out_size, void* d_ws, size_t ws_size,
                              hipStream_t stream) {
    (void)in_sizes; (void)n_in; (void)out_size; (void)ws_size;
    const float* hidden = (const float*)d_in[0];
    const float* Wq = (const float*)d_in[1];
    const float* Wk = (const float*)d_in[2];
    const float* Wv = (const float*)d_in[3];
    const float* Wo = (const float*)d_in[4];
    const float* qw = (const float*)d_in[5];
    const float* kw = (const float*)d_in[6];
    const int* pos = (const int*)d_in[7];
    float* out = (float*)d_out;
    char* ws = (char*)d_ws;

    const size_t MB = 1024 * 1024;
    signed char* x_i8  = (signed char*)(ws);            // 4 MB (tiled)
    signed char* wq_i8 = (signed char*)(ws + 4 * MB);   // 4 MB (tiled)
    signed char* wk_i8 = (signed char*)(ws + 8 * MB);   // 2 MB (tiled)
    signed char* wv_i8 = (signed char*)(ws + 10 * MB);  // 2 MB (tiled)
    signed char* wo_i8 = (signed char*)(ws + 12 * MB);  // 4 MB (tiled)
    signed char* q_i8  = (signed char*)(ws + 16 * MB);  // 4 MB (attn-tiled)
    signed char* k_i8  = (signed char*)(ws + 20 * MB);  // 2 MB (attn-tiled)
    float* sx  = (float*)(ws + 22 * MB);
    float* swq = sx + 2048;
    float* swk = swq + 2048;
    float* swv = swk + 1024;
    float* swo = swv + 1024;
    float* sq  = swo + 2048;                            // 16*2048
    float* sk  = sq + NH * SEQ;                         // 8*2048
    float* sa  = sk + NKV * SEQ;                        // 2048
    float* ct  = (float*)(ws + 22 * MB + 512 * 1024);   // 512 KB
    float* st  = (float*)(ws + 22 * MB + 1024 * 1024);  // 512 KB
    float* q_lin = (float*)(ws + 24 * MB);              // 16 MB -> attn2
    float* k_lin = (float*)(ws + 40 * MB);              // 8 MB  -> pp
    float* v_lin = (float*)(ws + 48 * MB);              // 8 MB  -> vtT
    unsigned short* vtT = (unsigned short*)(ws + 48 * MB); // 8 MB (aliases dead v_lin)
    float* v_dq = (float*)(ws + 56 * MB);               // 8 MB  -> mz after vt_split
    float* mz   = (float*)(ws + 56 * MB);               // 1 MB (aliases dead v_dq)
    float* pp   = (float*)(ws + 40 * MB);               // 8 MB (aliases dead k_lin)
    float* attn2 = q_lin;
    signed char* a_i8 = x_i8;

    rope_tab_k<<<2048, 64, 0, stream>>>(pos, ct, st);
    row_quant_k<<<128, 256, 0, stream>>>(hidden, x_i8, sx, 2048);
    row_quant_k<<<128, 256, 0, stream>>>(Wq, wq_i8, swq, 2048);
    row_quant_k<<<64, 256, 0, stream>>>(Wk, wk_i8, swk, 2048);
    row_quant_k<<<64, 256, 0, stream>>>(Wv, wv_i8, swv, 2048);
    row_quant_k<<<128, 256, 0, stream>>>(Wo, wo_i8, swo, 2048);

    gemm_i8_k<<<dim3(16, 16), 256, 0, stream>>>(x_i8, sx, wq_i8, swq, q_lin, 2048, 2048, 2048);
    gemm_i8_k<<<dim3(8, 16), 256, 0, stream>>>(x_i8, sx, wk_i8, swk, k_lin, 2048, 1024, 2048);
    gemm_i8_k<<<dim3(8, 16), 256, 0, stream>>>(x_i8, sx, wv_i8, swv, v_lin, 2048, 1024, 2048);

    qkv_post_k<<<dim3(2048, 32), 128, 0, stream>>>(q_lin, k_lin, v_lin, qw, kw, ct, st,
                                                   q_i8, sq, k_i8, sk, v_dq);
    vt_split_k<<<dim3(32, 8), 256, 0, stream>>>(v_dq, vtT);

    attn_p1_k<<<dim3(128, 16), 256, 0, stream>>>(q_i8, sq, k_i8, sk, mz);
    attn_p2_k<<<dim3(64, 16), 256, 0, stream>>>(q_i8, sq, k_i8, sk, vtT, mz, attn2, pp);
    attn_red_k<<<dim3(16, 16), 256, 0, stream>>>(attn2, pp);

    row_quant_k<<<128, 256, 0, stream>>>(attn2, a_i8, sa, 2048);
    gemm_i8_k<<<dim3(16, 16), 256, 0, stream>>>(a_i8, sa, wo_i8, swo, out, 2048, 2048, 2048);
}

// Round 7
// 353.443 us; speedup vs baseline: 1.3400x; 1.0506x over previous
//
#include <hip/hip_runtime.h>
#include <math.h>

#define NH 16
#define NKV 8
#define HDIM 128
#define SEQ 2048
#define DMODEL 2048

typedef int   v4i __attribute__((ext_vector_type(4)));
typedef float v4f __attribute__((ext_vector_type(4)));
typedef __bf16 v8bf __attribute__((ext_vector_type(8)));

static constexpr float SM_SCALE = 0.08838834764831843f; // 128**-0.5

#define GLOBP(p) (__attribute__((address_space(1))) void*)(p)
#define LDSP(p)  (__attribute__((address_space(3))) void*)(p)
#define ASYNC16(g, l) __builtin_amdgcn_global_load_lds(GLOBP(g), LDSP(l), 16, 0, 0)

// Fragment-tiled i8 layout for X[R][K] (R%16==0, K%64==0):
// frag (r>>4, k>>6) is 1024B; within: byte = ((k>>4)&3)*256 + (r&15)*16 + (k&15).
// A wave fragment read/ASYNC16 is then base + lane*16 -> fully coalesced 1KB.

// ---------------- per-row symmetric int8 quant, 16 rows/block, coalesced tiled writes ----
__global__ __launch_bounds__(256) void row_quant_k(const float* __restrict__ in,
        signed char* __restrict__ out, float* __restrict__ scale, int cols) {
    int row0 = blockIdx.x * 16;
    int tid = threadIdx.x;
    __shared__ float srow[16];
    int r = tid >> 4, l16 = tid & 15;
    const float4* x4 = (const float4*)(in + (size_t)(row0 + r) * cols);
    int n4 = cols >> 2;
    float amax = 0.f;
    for (int c4 = l16; c4 < n4; c4 += 16) {
        float4 v = x4[c4];
        amax = fmaxf(amax, fmaxf(fmaxf(fabsf(v.x), fabsf(v.y)),
                                 fmaxf(fabsf(v.z), fabsf(v.w))));
    }
#pragma unroll
    for (int m = 1; m <= 8; m <<= 1) amax = fmaxf(amax, __shfl_xor(amax, m));
    if (l16 == 0) {
        float s = fmaxf(amax / 127.0f, 1e-8f);
        srow[r] = s;
        scale[row0 + r] = s;
    }
    __syncthreads();
    int nchunk = cols >> 4;
    int total = nchunk * 16;
    size_t obase = ((size_t)(row0 >> 4) * (cols >> 6)) << 10;
    for (int idx = tid; idx < total; idx += 256) {
        int f = idx >> 6, q = (idx >> 4) & 3, rr = idx & 15;
        const float* src = in + (size_t)(row0 + rr) * cols + f * 64 + q * 16;
        float s = srow[rr];
        unsigned int wds[4];
#pragma unroll
        for (int g = 0; g < 4; ++g) {
            float4 v = *(const float4*)(src + g * 4);
            int b0 = (int)fminf(fmaxf(rintf(v.x / s), -127.f), 127.f);
            int b1 = (int)fminf(fmaxf(rintf(v.y / s), -127.f), 127.f);
            int b2 = (int)fminf(fmaxf(rintf(v.z / s), -127.f), 127.f);
            int b3 = (int)fminf(fmaxf(rintf(v.w / s), -127.f), 127.f);
            wds[g] = (b0 & 255) | ((b1 & 255) << 8) | ((b2 & 255) << 16) | ((b3 & 255) << 24);
        }
        *(uint4*)(out + obase + (size_t)idx * 16) =
            make_uint4(wds[0], wds[1], wds[2], wds[3]);
    }
}

// ---------------- int8 GEMM on tiled A/B ----------------
__global__ __launch_bounds__(256) void gemm_i8_k(const signed char* __restrict__ A,
        const float* __restrict__ sa, const signed char* __restrict__ B,
        const float* __restrict__ sb, float* __restrict__ C, int M, int N, int K) {
    __shared__ __align__(16) signed char lsA[8192];
    __shared__ __align__(16) signed char lsB[8192];
    int tid = threadIdx.x;
    int w = tid >> 6, l = tid & 63;
    int wr = w >> 1, wc = w & 1;
    int lrow = l & 15;
    int m0 = blockIdx.y * 128, n0 = blockIdx.x * 128;
    int kb6 = K >> 6;
    v4i acc[4][4];
#pragma unroll
    for (int i = 0; i < 4; ++i)
#pragma unroll
        for (int j = 0; j < 4; ++j) acc[i][j] = (v4i){0, 0, 0, 0};

    for (int k0 = 0; k0 < K; k0 += 64) {
        __syncthreads();
#pragma unroll
        for (int a = 0; a < 2; ++a) {
            int f = a * 4 + w;
            ASYNC16(A + (((size_t)(((m0 >> 4) + f) * kb6 + (k0 >> 6))) << 10) + l * 16,
                    lsA + f * 1024);
            ASYNC16(B + (((size_t)(((n0 >> 4) + f) * kb6 + (k0 >> 6))) << 10) + l * 16,
                    lsB + f * 1024);
        }
        __syncthreads();
        v4i af[4], bf[4];
#pragma unroll
        for (int i = 0; i < 4; ++i) af[i] = *(const v4i*)(lsA + (wr * 4 + i) * 1024 + l * 16);
#pragma unroll
        for (int j = 0; j < 4; ++j) bf[j] = *(const v4i*)(lsB + (wc * 4 + j) * 1024 + l * 16);
#pragma unroll
        for (int i = 0; i < 4; ++i)
#pragma unroll
            for (int j = 0; j < 4; ++j)
                acc[i][j] = __builtin_amdgcn_mfma_i32_16x16x64_i8(af[i], bf[j], acc[i][j], 0, 0, 0);
    }
    int r0 = m0 + wr * 64, c0 = n0 + wc * 64;
    int lg = l >> 4;
    float sbv[4];
#pragma unroll
    for (int j = 0; j < 4; ++j) sbv[j] = sb[c0 + j * 16 + lrow];
#pragma unroll
    for (int i = 0; i < 4; ++i) {
        float4 s4 = *(const float4*)(sa + r0 + i * 16 + lg * 4);
        float sav[4] = {s4.x, s4.y, s4.z, s4.w};
#pragma unroll
        for (int j = 0; j < 4; ++j) {
#pragma unroll
            for (int reg = 0; reg < 4; ++reg) {
                int rr = r0 + i * 16 + lg * 4 + reg;
                C[(size_t)rr * N + c0 + j * 16 + lrow] = (float)acc[i][j][reg] * (sav[reg] * sbv[j]);
            }
        }
    }
}

// ---------------- rope cos/sin table ----------------
__global__ void rope_tab_k(const int* __restrict__ pos_ids,
                           float* __restrict__ ct, float* __restrict__ st) {
    int t = blockIdx.x;
    int fi = threadIdx.x; // 64
    float pw = (float)pow(1.0e6, (double)fi / 64.0);
    float inv = 1.0f / pw;
    float fr = (float)pos_ids[t] * inv;
    float sn, c;
    sincosf(fr, &sn, &c);
    ct[t * 64 + fi] = c;
    st[t * 64 + fi] = sn;
}

// ---------------- rmsnorm + rope; q/k -> TILED int8 + scale, v -> fp32 ----------------
__global__ __launch_bounds__(128) void qkv_post_k(const float* __restrict__ q_lin,
        const float* __restrict__ k_lin, const float* __restrict__ v_lin,
        const float* __restrict__ qw, const float* __restrict__ kw,
        const float* __restrict__ ct, const float* __restrict__ st,
        signed char* __restrict__ q_i8, float* __restrict__ sq,
        signed char* __restrict__ k_i8, float* __restrict__ sk,
        float* __restrict__ v_dq) {
    int t = blockIdx.x;
    int hh = blockIdx.y;
    int d = threadIdx.x;
    __shared__ float xs[HDIM];
    __shared__ float red[2];
    float x;
    if (hh < NH)            x = q_lin[(size_t)t * DMODEL + hh * HDIM + d];
    else if (hh < NH + NKV) x = k_lin[(size_t)t * (NKV * HDIM) + (hh - NH) * HDIM + d];
    else                    x = v_lin[(size_t)t * (NKV * HDIM) + (hh - NH - NKV) * HDIM + d];

    if (hh < NH + NKV) {
        float sqv = x * x;
#pragma unroll
        for (int m = 32; m; m >>= 1) sqv += __shfl_xor(sqv, m);
        if ((d & 63) == 0) red[d >> 6] = sqv;
        __syncthreads();
        float mv = (red[0] + red[1]) / 128.0f;
        float rs = 1.0f / sqrtf(mv + 1e-6f);
        x = (x * rs) * ((hh < NH) ? qw[d] : kw[d]);
        xs[d] = x;
        __syncthreads();
        float other = (d < 64) ? xs[d + 64] : xs[d - 64];
        int fi = d & 63;
        float c = ct[t * 64 + fi];
        float sn = st[t * 64 + fi];
        x = (d < 64) ? (x * c - other * sn) : (x * c + other * sn);
        __syncthreads();
    }
    float amax = fabsf(x);
#pragma unroll
    for (int m = 32; m; m >>= 1) amax = fmaxf(amax, __shfl_xor(amax, m));
    if ((d & 63) == 0) red[d >> 6] = amax;
    __syncthreads();
    float s = fmaxf(fmaxf(red[0], red[1]) / 127.0f, 1e-8f);
    float qf = fminf(fmaxf(rintf(x / s), -127.f), 127.f);
    size_t ta = (size_t)(((t >> 4) * 2 + (d >> 6)) << 10)
              + (size_t)((((d >> 4) & 3) << 8) + ((t & 15) << 4) + (d & 15));
    if (hh < NH) {
        q_i8[(size_t)hh * (SEQ * 128) + ta] = (signed char)(int)qf;
        if (d == 0) sq[hh * SEQ + t] = s;
    } else if (hh < NH + NKV) {
        k_i8[(size_t)(hh - NH) * (SEQ * 128) + ta] = (signed char)(int)qf;
        if (d == 0) sk[(hh - NH) * SEQ + t] = s;
    } else {
        v_dq[(size_t)(hh - NH - NKV) * (SEQ * HDIM) + (size_t)t * HDIM + d] = qf * s;
    }
}

// ---------------- bf16 helpers ----------------
__device__ __forceinline__ unsigned int f2bf(float x) {
    unsigned int u = __float_as_uint(x);
    return (u + 0x7fffu + ((u >> 16) & 1u)) >> 16;
}
__device__ __forceinline__ float bf2f(unsigned int h) {
    return __uint_as_float(h << 16);
}

// ---------------- V transpose + bf16 split into MFMA-fragment-tiled vtT ----------------
__global__ __launch_bounds__(256) void vt_split_k(const float* __restrict__ v_dq,
        unsigned short* __restrict__ vtT) {
    int kv = blockIdx.y, kb = blockIdx.x;
    int t0 = kb * 64;
    __shared__ float tile[64][132];
    int tid = threadIdx.x;
    const float* src = v_dq + ((size_t)kv * SEQ + t0) * HDIM;
#pragma unroll
    for (int i = 0; i < 8; ++i) {
        int f4 = i * 256 + tid;
        int r = f4 >> 5, c = (f4 & 31) << 2;
        float4 v = *(const float4*)(src + r * HDIM + c);
        tile[r][c] = v.x; tile[r][c + 1] = v.y; tile[r][c + 2] = v.z; tile[r][c + 3] = v.w;
    }
    __syncthreads();
    int d = tid >> 1, th = (tid & 1) * 32;
    size_t base_hi = (size_t)(kv * 2 + 0) * (SEQ * 128);
    size_t base_lo = (size_t)(kv * 2 + 1) * (SEQ * 128);
#pragma unroll
    for (int j = 0; j < 32; j += 2) {
        int tl = th + j;
        float a = tile[tl][d], b = tile[tl + 1][d];
        unsigned int ah = f2bf(a), bh = f2bf(b);
        unsigned int al = f2bf(a - bf2f(ah)), bl = f2bf(b - bf2f(bh));
        int off = kb * 8192 + ((d >> 4) * 2 + ((tl >> 5) & 1)) * 512
                + (((d & 15) + (((tl >> 3) & 3) << 4)) << 3) + (tl & 7);
        *(unsigned int*)(vtT + base_hi + off) = ah | (bh << 16);
        *(unsigned int*)(vtT + base_lo + off) = al | (bl << 16);
    }
}

// ---------------- attention pass 1 (split-K): partial row MAX only ----------------
__global__ __launch_bounds__(256, 4) void attn_p1_k(const signed char* __restrict__ q_i8,
        const float* __restrict__ sq, const signed char* __restrict__ k_i8,
        const float* __restrict__ sk, float* __restrict__ mm) {
    int bx = blockIdx.x, h = blockIdx.y, kvh = h >> 1;
    int qb = 31 - (bx >> 2), c = bx & 3;
    int nch = (qb + 8) >> 3;
    if (c >= nch) return;
    int q0 = qb * 64;
    int kb0 = c * 8, kb1 = min((c + 1) * 8, qb + 1);
    int tid = threadIdx.x, w = tid >> 6, l = tid & 63;
    int lrow = l & 15, lg = l >> 4;

    const signed char* qt = q_i8 + (size_t)h * (SEQ * 128)
                          + ((size_t)((((q0 >> 4) + w) * 2)) << 10) + l * 16;
    v4i qf0 = *(const v4i*)(qt);
    v4i qf1 = *(const v4i*)(qt + 1024);
    float4 s4 = *(const float4*)(sq + (size_t)h * SEQ + q0 + w * 16 + lg * 4);
    float sqr[4] = {s4.x, s4.y, s4.z, s4.w};
    const signed char* kbase = k_i8 + (size_t)kvh * (SEQ * 128);
    const float* skb = sk + (size_t)kvh * SEQ;

    float m_l[4];
#pragma unroll
    for (int r = 0; r < 4; ++r) m_l[r] = -1e30f;

    v4i ka[8], kn[8];
    float skc[4], skn[4];
    auto loadK = [&](v4i* dst, float* sdst, int k0) {
#pragma unroll
        for (int f = 0; f < 8; ++f)
            dst[f] = *(const v4i*)(kbase + ((size_t)((k0 >> 4) * 2 + f) << 10) + l * 16);
#pragma unroll
        for (int j = 0; j < 4; ++j) sdst[j] = skb[k0 + j * 16 + lrow];
    };

    loadK(ka, skc, kb0 * 64);
    for (int kb = kb0; kb < kb1; ++kb) {
        if (kb + 1 < kb1) loadK(kn, skn, (kb + 1) * 64);
        int k0 = kb * 64;
        v4i sci[4];
#pragma unroll
        for (int j = 0; j < 4; ++j) {
            v4i z = {0, 0, 0, 0};
            v4i t0 = __builtin_amdgcn_mfma_i32_16x16x64_i8(qf0, ka[j * 2], z, 0, 0, 0);
            sci[j] = __builtin_amdgcn_mfma_i32_16x16x64_i8(qf1, ka[j * 2 + 1], t0, 0, 0, 0);
        }
#pragma unroll
        for (int reg = 0; reg < 4; ++reg) {
            int r = q0 + w * 16 + lg * 4 + reg;
#pragma unroll
            for (int j = 0; j < 4; ++j) {
                float sv = ((float)sci[j][reg] * (sqr[reg] * skc[j])) * SM_SCALE;
                m_l[reg] = fmaxf(m_l[reg], (k0 + j * 16 + lrow <= r) ? sv : -1e30f);
            }
        }
        if (kb + 1 < kb1) {
#pragma unroll
            for (int f = 0; f < 8; ++f) ka[f] = kn[f];
#pragma unroll
            for (int j = 0; j < 4; ++j) skc[j] = skn[j];
        }
    }
#pragma unroll
    for (int reg = 0; reg < 4; ++reg) {
#pragma unroll
        for (int mask = 1; mask <= 8; mask <<= 1)
            m_l[reg] = fmaxf(m_l[reg], __shfl_xor(m_l[reg], mask));
    }
    if (lrow == 0) {
        size_t base = ((size_t)(h * 32 + qb) * 4 + c) * 64;
#pragma unroll
        for (int reg = 0; reg < 4; ++reg)
            mm[base + w * 16 + lg * 4 + reg] = m_l[reg];
    }
}

// ---------------- attention pass 2 (split-K PV): K+V prefetch via LDS, Z in-pass ----------------
// LDS: V dbuf 64K + K 8K + plds 8K = 80KB -> 2 blocks/CU. No register prefetch (regalloc-proof).
__global__ __launch_bounds__(256, 2) void attn_p2_k(const signed char* __restrict__ q_i8,
        const float* __restrict__ sq, const signed char* __restrict__ k_i8,
        const float* __restrict__ sk, const unsigned short* __restrict__ vtT,
        const float* __restrict__ mm, float* __restrict__ attn2, float* __restrict__ pp,
        float* __restrict__ zb) {
    __shared__ __align__(16) unsigned short vlds[2][16384]; // 64 KB
    __shared__ __align__(16) signed char klds[8192];        // 8 KB
    __shared__ __align__(16) unsigned short plds[4096];     // 8 KB wave-private
    int bx = blockIdx.x, h = blockIdx.y, kvh = h >> 1;
    int qb = 31 - (bx >> 1), c = bx & 1;
    int nch2 = (qb >= 16) ? 2 : 1;
    if (c >= nch2) return;
    int q0 = qb * 64;
    int kb0 = c * 16, kb1 = min((c + 1) * 16, qb + 1);
    int tid = threadIdx.x, w = tid >> 6, l = tid & 63;
    int lrow = l & 15, lg = l >> 4;

    const signed char* qt = q_i8 + (size_t)h * (SEQ * 128)
                          + ((size_t)((((q0 >> 4) + w) * 2)) << 10) + l * 16;
    v4i qf0 = *(const v4i*)(qt);
    v4i qf1 = *(const v4i*)(qt + 1024);
    float4 s4 = *(const float4*)(sq + (size_t)h * SEQ + q0 + w * 16 + lg * 4);
    float sqr[4] = {s4.x, s4.y, s4.z, s4.w};

    // final row max from pass-1 partials (order-free max combine)
    int nch1 = (qb + 8) >> 3;
    float m_fin[4];
#pragma unroll
    for (int reg = 0; reg < 4; ++reg) {
        int r = w * 16 + lg * 4 + reg;
        float M = -1e30f;
        for (int c1 = 0; c1 < nch1; ++c1)
            M = fmaxf(M, mm[((size_t)(h * 32 + qb) * 4 + c1) * 64 + r]);
        m_fin[reg] = M;
    }

    const signed char* kbase = k_i8 + (size_t)kvh * (SEQ * 128);
    const float* skb = sk + (size_t)kvh * SEQ;
    const unsigned short* vt_h = vtT + (size_t)(kvh * 2 + 0) * (SEQ * 128);
    const unsigned short* vt_l = vtT + (size_t)(kvh * 2 + 1) * (SEQ * 128);

    auto issueV = [&](int kb) {
        unsigned short* vb = &vlds[kb & 1][0];
#pragma unroll
        for (int a = 0; a < 8; ++a) {
            int fv = a * 4 + w;
            int sp_ = fv >> 4, fr = fv & 15;
            const unsigned short* vsrc = (sp_ ? vt_l : vt_h) + kb * 8192 + fr * 512 + l * 8;
            ASYNC16(vsrc, vb + fv * 512);
        }
    };
    auto issueK = [&](int kb) {
#pragma unroll
        for (int a = 0; a < 2; ++a) {
            int f = a * 4 + w;
            ASYNC16(kbase + ((size_t)(kb * 8 + f) << 10) + l * 16, klds + f * 1024);
        }
    };

    v4f acco[8];
#pragma unroll
    for (int jd = 0; jd < 8; ++jd) acco[jd] = (v4f){0.f, 0.f, 0.f, 0.f};
    float zt[4] = {0.f, 0.f, 0.f, 0.f};

    issueV(kb0);
    issueK(kb0);
    asm volatile("s_waitcnt vmcnt(0)" ::: "memory");
    __syncthreads();
    for (int kb = kb0; kb < kb1; ++kb) {
        int k0 = kb * 64;
        // K tile: LDS -> regs (lane-linear b128, conflict-free)
        v4i ka[8];
#pragma unroll
        for (int f = 0; f < 8; ++f)
            ka[f] = *(const v4i*)(klds + f * 1024 + l * 16);
        float skc[4];
#pragma unroll
        for (int j = 0; j < 4; ++j) skc[j] = skb[k0 + j * 16 + lrow];
        v4i sci[4];
#pragma unroll
        for (int j = 0; j < 4; ++j) {
            v4i z = {0, 0, 0, 0};
            v4i t0 = __builtin_amdgcn_mfma_i32_16x16x64_i8(qf0, ka[j * 2], z, 0, 0, 0);
            sci[j] = __builtin_amdgcn_mfma_i32_16x16x64_i8(qf1, ka[j * 2 + 1], t0, 0, 0, 0);
        }
        // all waves have consumed klds (MFMA forced lgkmcnt wait) -> safe to overwrite
        __syncthreads();
        if (kb + 1 < kb1) {
            issueV(kb + 1);
            issueK(kb + 1);
        }
        // softmax + integer-p quant (needs only m_fin); Z accumulated here
#pragma unroll
        for (int reg = 0; reg < 4; ++reg) {
            int rq = lg * 4 + reg;
            int r = q0 + w * 16 + rq;
#pragma unroll
            for (int j = 0; j < 4; ++j) {
                int cc = j * 16 + lrow;
                float pd = 0.f;
                if (k0 + cc <= r) {
                    float sv = ((float)sci[j][reg] * (sqr[reg] * skc[j])) * SM_SCALE;
                    float e = __expf(sv - m_fin[reg]);
                    zt[reg] += e;
                    pd = fminf(rintf(127.0f * e), 127.f);
                }
                plds[(w * 2 + (cc >> 5)) * 512 + (rq + 16 * ((cc >> 3) & 3)) * 8 + (cc & 7)] =
                    (unsigned short)(__float_as_uint(pd) >> 16);
            }
        }
        v8bf pf0 = *(const v8bf*)(plds + (w * 2 + 0) * 512 + l * 8);
        v8bf pf1 = *(const v8bf*)(plds + (w * 2 + 1) * 512 + l * 8);
        const unsigned short* vb = &vlds[kb & 1][0];
#pragma unroll
        for (int jd = 0; jd < 8; ++jd) {
            v8bf vh0 = *(const v8bf*)(vb + (jd * 2 + 0) * 512 + l * 8);
            v8bf vh1 = *(const v8bf*)(vb + (jd * 2 + 1) * 512 + l * 8);
            v8bf vl0 = *(const v8bf*)(vb + (16 + jd * 2 + 0) * 512 + l * 8);
            v8bf vl1 = *(const v8bf*)(vb + (16 + jd * 2 + 1) * 512 + l * 8);
            v4f t = acco[jd];
            t = __builtin_amdgcn_mfma_f32_16x16x32_bf16(pf0, vh0, t, 0, 0, 0);
            t = __builtin_amdgcn_mfma_f32_16x16x32_bf16(pf1, vh1, t, 0, 0, 0);
            t = __builtin_amdgcn_mfma_f32_16x16x32_bf16(pf0, vl0, t, 0, 0, 0);
            t = __builtin_amdgcn_mfma_f32_16x16x32_bf16(pf1, vl1, t, 0, 0, 0);
            acco[jd] = t;
        }
        asm volatile("s_waitcnt vmcnt(0)" ::: "memory");
        __syncthreads();
    }
    // per-row Z: butterfly over the 16 lanes sharing a row
#pragma unroll
    for (int reg = 0; reg < 4; ++reg) {
#pragma unroll
        for (int mask = 1; mask <= 8; mask <<= 1)
            zt[reg] += __shfl_xor(zt[reg], mask);
    }
    if (qb < 16) {
        // single chunk: finalize here
        float spv[4];
#pragma unroll
        for (int reg = 0; reg < 4; ++reg) {
            float zinv = 1.0f / zt[reg];
            spv[reg] = fmaxf(zinv / 127.0f, 1e-8f);
        }
#pragma unroll
        for (int jd = 0; jd < 8; ++jd)
#pragma unroll
            for (int reg = 0; reg < 4; ++reg) {
                int r = q0 + w * 16 + lg * 4 + reg;
                attn2[(size_t)r * DMODEL + h * HDIM + jd * 16 + lrow] = acco[jd][reg] * spv[reg];
            }
    } else {
        // write raw partials + Z partial; attn_red finalizes
        if (c == 0) {
#pragma unroll
            for (int jd = 0; jd < 8; ++jd)
#pragma unroll
                for (int reg = 0; reg < 4; ++reg) {
                    int r = q0 + w * 16 + lg * 4 + reg;
                    attn2[(size_t)r * DMODEL + h * HDIM + jd * 16 + lrow] = acco[jd][reg];
                }
        } else {
#pragma unroll
            for (int jd = 0; jd < 8; ++jd)
#pragma unroll
                for (int reg = 0; reg < 4; ++reg) {
                    int rr = w * 16 + lg * 4 + reg;
                    pp[(((size_t)h * 16 + (qb - 16)) * 64 + rr) * 128 + jd * 16 + lrow] =
                        acco[jd][reg];
                }
        }
        if (lrow == 0) {
            size_t zbase = (((size_t)h * 16 + (qb - 16)) * 2 + c) * 64;
#pragma unroll
            for (int reg = 0; reg < 4; ++reg)
                zb[zbase + w * 16 + lg * 4 + reg] = zt[reg];
        }
    }
}

// ---------------- reduce: out = (chunk0 + chunk1) * spv(Z0+Z1), tiles qb>=16 ----------------
__global__ __launch_bounds__(256) void attn_red_k(float* __restrict__ attn2,
        const float* __restrict__ pp, const float* __restrict__ zb) {
    int t16 = blockIdx.x, h = blockIdx.y;
    int qb = t16 + 16;
    int tid = threadIdx.x;
    for (int e = tid; e < 2048; e += 256) {
        int i = (e * 4) >> 7, j = (e * 4) & 127;
        float z0 = zb[(((size_t)h * 16 + t16) * 2 + 0) * 64 + i];
        float z1 = zb[(((size_t)h * 16 + t16) * 2 + 1) * 64 + i];
        float zinv = 1.0f / (z0 + z1);
        float spv = fmaxf(zinv / 127.0f, 1e-8f);
        float4 p = *(const float4*)&pp[(((size_t)h * 16 + t16) * 64 + i) * 128 + j];
        float* d = &attn2[(size_t)(qb * 64 + i) * DMODEL + h * HDIM + j];
        float4 dv = *(float4*)d;
        dv.x = (dv.x + p.x) * spv; dv.y = (dv.y + p.y) * spv;
        dv.z = (dv.z + p.z) * spv; dv.w = (dv.w + p.w) * spv;
        *(float4*)d = dv;
    }
}

extern "C" void kernel_launch(void* const* d_in, const int* in_sizes, int n_in,
                              void* d_out, int out_size, void* d_ws, size_t ws_size,
                              hipStream_t stream) {
    (void)in_sizes; (void)n_in; (void)out_size; (void)ws_size;
    const float* hidden = (const float*)d_in[0];
    const float* Wq = (const float*)d_in[1];
    const float* Wk = (const float*)d_in[2];
    const float* Wv = (const float*)d_in[3];
    const float* Wo = (const float*)d_in[4];
    const float* qw = (const float*)d_in[5];
    const float* kw = (const float*)d_in[6];
    const int* pos = (const int*)d_in[7];
    float* out = (float*)d_out;
    char* ws = (char*)d_ws;

    const size_t MB = 1024 * 1024;
    signed char* x_i8  = (signed char*)(ws);            // 4 MB (tiled)
    signed char* wq_i8 = (signed char*)(ws + 4 * MB);   // 4 MB
    signed char* wk_i8 = (signed char*)(ws + 8 * MB);   // 2 MB
    signed char* wv_i8 = (signed char*)(ws + 10 * MB);  // 2 MB
    signed char* wo_i8 = (signed char*)(ws + 12 * MB);  // 4 MB
    signed char* q_i8  = (signed char*)(ws + 16 * MB);  // 4 MB (attn-tiled)
    signed char* k_i8  = (signed char*)(ws + 20 * MB);  // 2 MB (attn-tiled)
    float* sx  = (float*)(ws + 22 * MB);
    float* swq = sx + 2048;
    float* swk = swq + 2048;
    float* swv = swk + 1024;
    float* swo = swv + 1024;
    float* sq  = swo + 2048;                            // 16*2048
    float* sk  = sq + NH * SEQ;                         // 8*2048
    float* sa  = sk + NKV * SEQ;                        // 2048
    float* ct  = (float*)(ws + 22 * MB + 512 * 1024);   // 512 KB
    float* st  = (float*)(ws + 22 * MB + 1024 * 1024);  // 512 KB
    float* q_lin = (float*)(ws + 24 * MB);              // 16 MB -> attn2
    float* k_lin = (float*)(ws + 40 * MB);              // 8 MB  -> pp
    float* v_lin = (float*)(ws + 48 * MB);              // 8 MB  -> vtT
    unsigned short* vtT = (unsigned short*)(ws + 48 * MB);
    float* v_dq = (float*)(ws + 56 * MB);               // 8 MB -> mm/zb after vt_split
    float* mm   = (float*)(ws + 56 * MB);               // 512 KB (dead v_dq)
    float* zb   = (float*)(ws + 57 * MB);               // 128 KB
    float* pp   = (float*)(ws + 40 * MB);               // 8 MB (dead k_lin)
    float* attn2 = q_lin;
    signed char* a_i8 = x_i8;

    rope_tab_k<<<2048, 64, 0, stream>>>(pos, ct, st);
    row_quant_k<<<128, 256, 0, stream>>>(hidden, x_i8, sx, 2048);
    row_quant_k<<<128, 256, 0, stream>>>(Wq, wq_i8, swq, 2048);
    row_quant_k<<<64, 256, 0, stream>>>(Wk, wk_i8, swk, 2048);
    row_quant_k<<<64, 256, 0, stream>>>(Wv, wv_i8, swv, 2048);
    row_quant_k<<<128, 256, 0, stream>>>(Wo, wo_i8, swo, 2048);

    gemm_i8_k<<<dim3(16, 16), 256, 0, stream>>>(x_i8, sx, wq_i8, swq, q_lin, 2048, 2048, 2048);
    gemm_i8_k<<<dim3(8, 16), 256, 0, stream>>>(x_i8, sx, wk_i8, swk, k_lin, 2048, 1024, 2048);
    gemm_i8_k<<<dim3(8, 16), 256, 0, stream>>>(x_i8, sx, wv_i8, swv, v_lin, 2048, 1024, 2048);

    qkv_post_k<<<dim3(2048, 32), 128, 0, stream>>>(q_lin, k_lin, v_lin, qw, kw, ct, st,
                                                   q_i8, sq, k_i8, sk, v_dq);
    vt_split_k<<<dim3(32, 8), 256, 0, stream>>>(v_dq, vtT);

    attn_p1_k<<<dim3(128, 16), 256, 0, stream>>>(q_i8, sq, k_i8, sk, mm);
    attn_p2_k<<<dim3(64, 16), 256, 0, stream>>>(q_i8, sq, k_i8, sk, vtT, mm, attn2, pp, zb);
    attn_red_k<<<dim3(16, 16), 256, 0, stream>>>(attn2, pp, zb);

    row_quant_k<<<128, 256, 0, stream>>>(attn2, a_i8, sa, 2048);
    gemm_i8_k<<<dim3(16, 16), 256, 0, stream>>>(a_i8, sa, wo_i8, swo, out, 2048, 2048, 2048);
}

// Round 8
// 282.654 us; speedup vs baseline: 1.6756x; 1.2504x over previous
//
#include <hip/hip_runtime.h>
#include <math.h>

#define NH 16
#define NKV 8
#define HDIM 128
#define SEQ 2048
#define DMODEL 2048

typedef int   v4i __attribute__((ext_vector_type(4)));
typedef float v4f __attribute__((ext_vector_type(4)));
typedef __bf16 v8bf __attribute__((ext_vector_type(8)));

static constexpr float SM_SCALE = 0.08838834764831843f; // 128**-0.5

#define GLOBP(p) (__attribute__((address_space(1))) void*)(p)
#define LDSP(p)  (__attribute__((address_space(3))) void*)(p)
#define ASYNC16(g, l) __builtin_amdgcn_global_load_lds(GLOBP(g), LDSP(l), 16, 0, 0)

// Fragment-tiled i8 layout for X[R][K] (R%16==0, K%64==0):
// frag (r>>4, k>>6) is 1024B; within: byte = ((k>>4)&3)*256 + (r&15)*16 + (k&15).
// A wave fragment read/ASYNC16 is then base + lane*16 -> fully coalesced 1KB.

// ---------------- per-row symmetric int8 quant, 16 rows/block, coalesced tiled writes ----
__global__ __launch_bounds__(256) void row_quant_k(const float* __restrict__ in,
        signed char* __restrict__ out, float* __restrict__ scale, int cols) {
    int row0 = blockIdx.x * 16;
    int tid = threadIdx.x;
    __shared__ float srow[16];
    int r = tid >> 4, l16 = tid & 15;
    const float4* x4 = (const float4*)(in + (size_t)(row0 + r) * cols);
    int n4 = cols >> 2;
    float amax = 0.f;
    for (int c4 = l16; c4 < n4; c4 += 16) {
        float4 v = x4[c4];
        amax = fmaxf(amax, fmaxf(fmaxf(fabsf(v.x), fabsf(v.y)),
                                 fmaxf(fabsf(v.z), fabsf(v.w))));
    }
#pragma unroll
    for (int m = 1; m <= 8; m <<= 1) amax = fmaxf(amax, __shfl_xor(amax, m));
    if (l16 == 0) {
        float s = fmaxf(amax / 127.0f, 1e-8f);
        srow[r] = s;
        scale[row0 + r] = s;
    }
    __syncthreads();
    int total = (cols >> 4) * 16;
    size_t obase = ((size_t)(row0 >> 4) * (cols >> 6)) << 10;
    for (int idx = tid; idx < total; idx += 256) {
        int f = idx >> 6, q = (idx >> 4) & 3, rr = idx & 15;
        const float* src = in + (size_t)(row0 + rr) * cols + f * 64 + q * 16;
        float s = srow[rr];
        unsigned int wds[4];
#pragma unroll
        for (int g = 0; g < 4; ++g) {
            float4 v = *(const float4*)(src + g * 4);
            int b0 = (int)fminf(fmaxf(rintf(v.x / s), -127.f), 127.f);
            int b1 = (int)fminf(fmaxf(rintf(v.y / s), -127.f), 127.f);
            int b2 = (int)fminf(fmaxf(rintf(v.z / s), -127.f), 127.f);
            int b3 = (int)fminf(fmaxf(rintf(v.w / s), -127.f), 127.f);
            wds[g] = (b0 & 255) | ((b1 & 255) << 8) | ((b2 & 255) << 16) | ((b3 & 255) << 24);
        }
        *(uint4*)(out + obase + (size_t)idx * 16) =
            make_uint4(wds[0], wds[1], wds[2], wds[3]);
    }
}

// ---------------- int8 GEMM on tiled A/B, double-buffered LDS pipeline ----------------
__global__ __launch_bounds__(256, 2) void gemm_i8_k(const signed char* __restrict__ A,
        const float* __restrict__ sa, const signed char* __restrict__ B,
        const float* __restrict__ sb, float* __restrict__ C, int M, int N, int K) {
    __shared__ __align__(16) signed char lsA[2][8192];
    __shared__ __align__(16) signed char lsB[2][8192];
    int tid = threadIdx.x;
    int w = tid >> 6, l = tid & 63;
    int wr = w >> 1, wc = w & 1;
    int lrow = l & 15;
    int m0 = blockIdx.y * 128, n0 = blockIdx.x * 128;
    int kb6 = K >> 6;
    v4i acc[4][4];
#pragma unroll
    for (int i = 0; i < 4; ++i)
#pragma unroll
        for (int j = 0; j < 4; ++j) acc[i][j] = (v4i){0, 0, 0, 0};

    auto stage = [&](int buf, int k6) {
#pragma unroll
        for (int a = 0; a < 2; ++a) {
            int f = a * 4 + w;
            ASYNC16(A + (((size_t)(((m0 >> 4) + f) * kb6 + k6)) << 10) + l * 16,
                    lsA[buf] + f * 1024);
            ASYNC16(B + (((size_t)(((n0 >> 4) + f) * kb6 + k6)) << 10) + l * 16,
                    lsB[buf] + f * 1024);
        }
    };

    stage(0, 0);
    asm volatile("s_waitcnt vmcnt(0)" ::: "memory");
    __syncthreads();
    int cur = 0;
    for (int t = 0; t < kb6; ++t) {
        if (t + 1 < kb6) stage(cur ^ 1, t + 1);   // overlap next fetch with this compute
        v4i af[4], bf[4];
#pragma unroll
        for (int i = 0; i < 4; ++i) af[i] = *(const v4i*)(lsA[cur] + (wr * 4 + i) * 1024 + l * 16);
#pragma unroll
        for (int j = 0; j < 4; ++j) bf[j] = *(const v4i*)(lsB[cur] + (wc * 4 + j) * 1024 + l * 16);
#pragma unroll
        for (int i = 0; i < 4; ++i)
#pragma unroll
            for (int j = 0; j < 4; ++j)
                acc[i][j] = __builtin_amdgcn_mfma_i32_16x16x64_i8(af[i], bf[j], acc[i][j], 0, 0, 0);
        asm volatile("s_waitcnt vmcnt(0)" ::: "memory");
        __syncthreads();
        cur ^= 1;
    }
    int r0 = m0 + wr * 64, c0 = n0 + wc * 64;
    int lg = l >> 4;
    float sbv[4];
#pragma unroll
    for (int j = 0; j < 4; ++j) sbv[j] = sb[c0 + j * 16 + lrow];
#pragma unroll
    for (int i = 0; i < 4; ++i) {
        float4 s4 = *(const float4*)(sa + r0 + i * 16 + lg * 4);
        float sav[4] = {s4.x, s4.y, s4.z, s4.w};
#pragma unroll
        for (int j = 0; j < 4; ++j) {
#pragma unroll
            for (int reg = 0; reg < 4; ++reg) {
                int rr = r0 + i * 16 + lg * 4 + reg;
                C[(size_t)rr * N + c0 + j * 16 + lrow] = (float)acc[i][j][reg] * (sav[reg] * sbv[j]);
            }
        }
    }
}

// ---------------- rope tables ----------------
__global__ void rope_init_k(float* __restrict__ inv_tab) {
    int i = threadIdx.x; // 64
    inv_tab[i] = 1.0f / (float)pow(1.0e6, (double)i / 64.0);
}
__global__ void rope_tab_k(const int* __restrict__ pos_ids, const float* __restrict__ inv_tab,
                           float* __restrict__ ct, float* __restrict__ st) {
    int t = blockIdx.x;
    int fi = threadIdx.x; // 64
    float fr = (float)pos_ids[t] * inv_tab[fi];
    float sn, c;
    sincosf(fr, &sn, &c);
    ct[t * 64 + fi] = c;
    st[t * 64 + fi] = sn;
}

// ---------------- fused rmsnorm+rope+quant, barrier-free: one token per block ----------------
// Wave handles a whole 128-row: lane l holds (d=l, d=l+64) — the rotate-half pair is in-lane.
__global__ __launch_bounds__(256) void qkv_post_k(const float* __restrict__ qkv_lin,
        const float* __restrict__ qw, const float* __restrict__ kw,
        const float* __restrict__ ct, const float* __restrict__ st,
        signed char* __restrict__ q_i8, float* __restrict__ sq,
        signed char* __restrict__ k_i8, float* __restrict__ sk,
        float* __restrict__ v_dq) {
    int t = blockIdx.x;
    int wv = threadIdx.x >> 6, l = threadIdx.x & 63;
    const float* row = qkv_lin + (size_t)t * 4096;
    float cth = ct[t * 64 + l];
    float sth = st[t * 64 + l];
    // tiled byte offset for (t, d=l) within a head panel; (t, d=l+64) is +1024
    size_t ta0 = (size_t)(((t >> 4) * 2) << 10)
               + (size_t)((((l >> 4) & 3) << 8) + ((t & 15) << 4) + (l & 15));
    for (int slot = wv; slot < 32; slot += 4) {
        float x0 = row[slot * 128 + l];
        float x1 = row[slot * 128 + l + 64];
        if (slot < 24) {    // q or k: rmsnorm + rope
            float ss = x0 * x0 + x1 * x1;
#pragma unroll
            for (int m = 1; m <= 32; m <<= 1) ss += __shfl_xor(ss, m);
            float rs = 1.0f / sqrtf(ss / 128.0f + 1e-6f);
            const float* wn = (slot < 16) ? qw : kw;
            x0 = (x0 * rs) * wn[l];
            x1 = (x1 * rs) * wn[l + 64];
            float nx0 = x0 * cth - x1 * sth;
            float nx1 = x1 * cth + x0 * sth;
            x0 = nx0; x1 = nx1;
        }
        float amax = fmaxf(fabsf(x0), fabsf(x1));
#pragma unroll
        for (int m = 1; m <= 32; m <<= 1) amax = fmaxf(amax, __shfl_xor(amax, m));
        float s = fmaxf(amax / 127.0f, 1e-8f);
        float q0 = fminf(fmaxf(rintf(x0 / s), -127.f), 127.f);
        float q1 = fminf(fmaxf(rintf(x1 / s), -127.f), 127.f);
        if (slot < 16) {
            signed char* dst = q_i8 + (size_t)slot * (SEQ * 128);
            dst[ta0] = (signed char)(int)q0;
            dst[ta0 + 1024] = (signed char)(int)q1;
            if (l == 0) sq[slot * SEQ + t] = s;
        } else if (slot < 24) {
            signed char* dst = k_i8 + (size_t)(slot - 16) * (SEQ * 128);
            dst[ta0] = (signed char)(int)q0;
            dst[ta0 + 1024] = (signed char)(int)q1;
            if (l == 0) sk[(slot - 16) * SEQ + t] = s;
        } else {
            float* dst = v_dq + ((size_t)(slot - 24) * SEQ + t) * HDIM;
            dst[l] = q0 * s;
            dst[l + 64] = q1 * s;
        }
    }
}

// ---------------- bf16 helpers ----------------
__device__ __forceinline__ unsigned int f2bf(float x) {
    unsigned int u = __float_as_uint(x);
    return (u + 0x7fffu + ((u >> 16) & 1u)) >> 16;
}
__device__ __forceinline__ float bf2f(unsigned int h) {
    return __uint_as_float(h << 16);
}

// ---------------- V transpose + bf16 split into MFMA-fragment-tiled vtT ----------------
__global__ __launch_bounds__(256) void vt_split_k(const float* __restrict__ v_dq,
        unsigned short* __restrict__ vtT) {
    int kv = blockIdx.y, kb = blockIdx.x;
    int t0 = kb * 64;
    __shared__ float tile[64][132];
    int tid = threadIdx.x;
    const float* src = v_dq + ((size_t)kv * SEQ + t0) * HDIM;
#pragma unroll
    for (int i = 0; i < 8; ++i) {
        int f4 = i * 256 + tid;
        int r = f4 >> 5, c = (f4 & 31) << 2;
        float4 v = *(const float4*)(src + r * HDIM + c);
        tile[r][c] = v.x; tile[r][c + 1] = v.y; tile[r][c + 2] = v.z; tile[r][c + 3] = v.w;
    }
    __syncthreads();
    int d = tid >> 1, th = (tid & 1) * 32;
    size_t base_hi = (size_t)(kv * 2 + 0) * (SEQ * 128);
    size_t base_lo = (size_t)(kv * 2 + 1) * (SEQ * 128);
#pragma unroll
    for (int j = 0; j < 32; j += 2) {
        int tl = th + j;
        float a = tile[tl][d], b = tile[tl + 1][d];
        unsigned int ah = f2bf(a), bh = f2bf(b);
        unsigned int al = f2bf(a - bf2f(ah)), bl = f2bf(b - bf2f(bh));
        int off = kb * 8192 + ((d >> 4) * 2 + ((tl >> 5) & 1)) * 512
                + (((d & 15) + (((tl >> 3) & 3) << 4)) << 3) + (tl & 7);
        *(unsigned int*)(vtT + base_hi + off) = ah | (bh << 16);
        *(unsigned int*)(vtT + base_lo + off) = al | (bl << 16);
    }
}

// ---------------- attention pass 1 (split-K): partial row MAX only ----------------
__global__ __launch_bounds__(256, 4) void attn_p1_k(const signed char* __restrict__ q_i8,
        const float* __restrict__ sq, const signed char* __restrict__ k_i8,
        const float* __restrict__ sk, float* __restrict__ mm) {
    int bx = blockIdx.x, h = blockIdx.y, kvh = h >> 1;
    int qb = 31 - (bx >> 2), c = bx & 3;
    int nch = (qb + 8) >> 3;
    if (c >= nch) return;
    int q0 = qb * 64;
    int kb0 = c * 8, kb1 = min((c + 1) * 8, qb + 1);
    int tid = threadIdx.x, w = tid >> 6, l = tid & 63;
    int lrow = l & 15, lg = l >> 4;

    const signed char* qt = q_i8 + (size_t)h * (SEQ * 128)
                          + ((size_t)((((q0 >> 4) + w) * 2)) << 10) + l * 16;
    v4i qf0 = *(const v4i*)(qt);
    v4i qf1 = *(const v4i*)(qt + 1024);
    float4 s4 = *(const float4*)(sq + (size_t)h * SEQ + q0 + w * 16 + lg * 4);
    float sqr[4] = {s4.x, s4.y, s4.z, s4.w};
    const signed char* kbase = k_i8 + (size_t)kvh * (SEQ * 128);
    const float* skb = sk + (size_t)kvh * SEQ;

    float m_l[4];
#pragma unroll
    for (int r = 0; r < 4; ++r) m_l[r] = -1e30f;

    v4i ka[8], kn[8];
    float skc[4], skn[4];
    auto loadK = [&](v4i* dst, float* sdst, int k0) {
#pragma unroll
        for (int f = 0; f < 8; ++f)
            dst[f] = *(const v4i*)(kbase + ((size_t)((k0 >> 4) * 2 + f) << 10) + l * 16);
#pragma unroll
        for (int j = 0; j < 4; ++j) sdst[j] = skb[k0 + j * 16 + lrow];
    };

    loadK(ka, skc, kb0 * 64);
    for (int kb = kb0; kb < kb1; ++kb) {
        if (kb + 1 < kb1) loadK(kn, skn, (kb + 1) * 64);
        int k0 = kb * 64;
        v4i sci[4];
#pragma unroll
        for (int j = 0; j < 4; ++j) {
            v4i z = {0, 0, 0, 0};
            v4i t0 = __builtin_amdgcn_mfma_i32_16x16x64_i8(qf0, ka[j * 2], z, 0, 0, 0);
            sci[j] = __builtin_amdgcn_mfma_i32_16x16x64_i8(qf1, ka[j * 2 + 1], t0, 0, 0, 0);
        }
#pragma unroll
        for (int reg = 0; reg < 4; ++reg) {
            int r = q0 + w * 16 + lg * 4 + reg;
#pragma unroll
            for (int j = 0; j < 4; ++j) {
                float sv = ((float)sci[j][reg] * (sqr[reg] * skc[j])) * SM_SCALE;
                m_l[reg] = fmaxf(m_l[reg], (k0 + j * 16 + lrow <= r) ? sv : -1e30f);
            }
        }
        if (kb + 1 < kb1) {
#pragma unroll
            for (int f = 0; f < 8; ++f) ka[f] = kn[f];
#pragma unroll
            for (int j = 0; j < 4; ++j) skc[j] = skn[j];
        }
    }
#pragma unroll
    for (int reg = 0; reg < 4; ++reg) {
#pragma unroll
        for (int mask = 1; mask <= 8; mask <<= 1)
            m_l[reg] = fmaxf(m_l[reg], __shfl_xor(m_l[reg], mask));
    }
    if (lrow == 0) {
        size_t base = ((size_t)(h * 32 + qb) * 4 + c) * 64;
#pragma unroll
        for (int reg = 0; reg < 4; ++reg)
            mm[base + w * 16 + lg * 4 + reg] = m_l[reg];
    }
}

// ---------------- attention pass 2 (split-K PV): K+V prefetch via LDS, Z in-pass ----------------
__global__ __launch_bounds__(256, 2) void attn_p2_k(const signed char* __restrict__ q_i8,
        const float* __restrict__ sq, const signed char* __restrict__ k_i8,
        const float* __restrict__ sk, const unsigned short* __restrict__ vtT,
        const float* __restrict__ mm, float* __restrict__ attn2, float* __restrict__ pp,
        float* __restrict__ zb) {
    __shared__ __align__(16) unsigned short vlds[2][16384]; // 64 KB
    __shared__ __align__(16) signed char klds[8192];        // 8 KB
    __shared__ __align__(16) unsigned short plds[4096];     // 8 KB wave-private
    int bx = blockIdx.x, h = blockIdx.y, kvh = h >> 1;
    int qb = 31 - (bx >> 1), c = bx & 1;
    int nch2 = (qb >= 16) ? 2 : 1;
    if (c >= nch2) return;
    int q0 = qb * 64;
    int kb0 = c * 16, kb1 = min((c + 1) * 16, qb + 1);
    int tid = threadIdx.x, w = tid >> 6, l = tid & 63;
    int lrow = l & 15, lg = l >> 4;

    const signed char* qt = q_i8 + (size_t)h * (SEQ * 128)
                          + ((size_t)((((q0 >> 4) + w) * 2)) << 10) + l * 16;
    v4i qf0 = *(const v4i*)(qt);
    v4i qf1 = *(const v4i*)(qt + 1024);
    float4 s4 = *(const float4*)(sq + (size_t)h * SEQ + q0 + w * 16 + lg * 4);
    float sqr[4] = {s4.x, s4.y, s4.z, s4.w};

    int nch1 = (qb + 8) >> 3;
    float m_fin[4];
#pragma unroll
    for (int reg = 0; reg < 4; ++reg) {
        int r = w * 16 + lg * 4 + reg;
        float M = -1e30f;
        for (int c1 = 0; c1 < nch1; ++c1)
            M = fmaxf(M, mm[((size_t)(h * 32 + qb) * 4 + c1) * 64 + r]);
        m_fin[reg] = M;
    }

    const signed char* kbase = k_i8 + (size_t)kvh * (SEQ * 128);
    const float* skb = sk + (size_t)kvh * SEQ;
    const unsigned short* vt_h = vtT + (size_t)(kvh * 2 + 0) * (SEQ * 128);
    const unsigned short* vt_l = vtT + (size_t)(kvh * 2 + 1) * (SEQ * 128);

    auto issueV = [&](int kb) {
        unsigned short* vb = &vlds[kb & 1][0];
#pragma unroll
        for (int a = 0; a < 8; ++a) {
            int fv = a * 4 + w;
            int sp_ = fv >> 4, fr = fv & 15;
            const unsigned short* vsrc = (sp_ ? vt_l : vt_h) + kb * 8192 + fr * 512 + l * 8;
            ASYNC16(vsrc, vb + fv * 512);
        }
    };
    auto issueK = [&](int kb) {
#pragma unroll
        for (int a = 0; a < 2; ++a) {
            int f = a * 4 + w;
            ASYNC16(kbase + ((size_t)(kb * 8 + f) << 10) + l * 16, klds + f * 1024);
        }
    };

    v4f acco[8];
#pragma unroll
    for (int jd = 0; jd < 8; ++jd) acco[jd] = (v4f){0.f, 0.f, 0.f, 0.f};
    float zt[4] = {0.f, 0.f, 0.f, 0.f};

    issueV(kb0);
    issueK(kb0);
    asm volatile("s_waitcnt vmcnt(0)" ::: "memory");
    __syncthreads();
    for (int kb = kb0; kb < kb1; ++kb) {
        int k0 = kb * 64;
        v4i ka[8];
#pragma unroll
        for (int f = 0; f < 8; ++f)
            ka[f] = *(const v4i*)(klds + f * 1024 + l * 16);
        float skc[4];
#pragma unroll
        for (int j = 0; j < 4; ++j) skc[j] = skb[k0 + j * 16 + lrow];
        v4i sci[4];
#pragma unroll
        for (int j = 0; j < 4; ++j) {
            v4i z = {0, 0, 0, 0};
            v4i t0 = __builtin_amdgcn_mfma_i32_16x16x64_i8(qf0, ka[j * 2], z, 0, 0, 0);
            sci[j] = __builtin_amdgcn_mfma_i32_16x16x64_i8(qf1, ka[j * 2 + 1], t0, 0, 0, 0);
        }
        __syncthreads();
        if (kb + 1 < kb1) {
            issueV(kb + 1);
            issueK(kb + 1);
        }
#pragma unroll
        for (int reg = 0; reg < 4; ++reg) {
            int rq = lg * 4 + reg;
            int r = q0 + w * 16 + rq;
#pragma unroll
            for (int j = 0; j < 4; ++j) {
                int cc = j * 16 + lrow;
                float pd = 0.f;
                if (k0 + cc <= r) {
                    float sv = ((float)sci[j][reg] * (sqr[reg] * skc[j])) * SM_SCALE;
                    float e = __expf(sv - m_fin[reg]);
                    zt[reg] += e;
                    pd = fminf(rintf(127.0f * e), 127.f);
                }
                plds[(w * 2 + (cc >> 5)) * 512 + (rq + 16 * ((cc >> 3) & 3)) * 8 + (cc & 7)] =
                    (unsigned short)(__float_as_uint(pd) >> 16);
            }
        }
        v8bf pf0 = *(const v8bf*)(plds + (w * 2 + 0) * 512 + l * 8);
        v8bf pf1 = *(const v8bf*)(plds + (w * 2 + 1) * 512 + l * 8);
        const unsigned short* vb = &vlds[kb & 1][0];
#pragma unroll
        for (int jd = 0; jd < 8; ++jd) {
            v8bf vh0 = *(const v8bf*)(vb + (jd * 2 + 0) * 512 + l * 8);
            v8bf vh1 = *(const v8bf*)(vb + (jd * 2 + 1) * 512 + l * 8);
            v8bf vl0 = *(const v8bf*)(vb + (16 + jd * 2 + 0) * 512 + l * 8);
            v8bf vl1 = *(const v8bf*)(vb + (16 + jd * 2 + 1) * 512 + l * 8);
            v4f t = acco[jd];
            t = __builtin_amdgcn_mfma_f32_16x16x32_bf16(pf0, vh0, t, 0, 0, 0);
            t = __builtin_amdgcn_mfma_f32_16x16x32_bf16(pf1, vh1, t, 0, 0, 0);
            t = __builtin_amdgcn_mfma_f32_16x16x32_bf16(pf0, vl0, t, 0, 0, 0);
            t = __builtin_amdgcn_mfma_f32_16x16x32_bf16(pf1, vl1, t, 0, 0, 0);
            acco[jd] = t;
        }
        asm volatile("s_waitcnt vmcnt(0)" ::: "memory");
        __syncthreads();
    }
#pragma unroll
    for (int reg = 0; reg < 4; ++reg) {
#pragma unroll
        for (int mask = 1; mask <= 8; mask <<= 1)
            zt[reg] += __shfl_xor(zt[reg], mask);
    }
    if (qb < 16) {
        float spv[4];
#pragma unroll
        for (int reg = 0; reg < 4; ++reg) {
            float zinv = 1.0f / zt[reg];
            spv[reg] = fmaxf(zinv / 127.0f, 1e-8f);
        }
#pragma unroll
        for (int jd = 0; jd < 8; ++jd)
#pragma unroll
            for (int reg = 0; reg < 4; ++reg) {
                int r = q0 + w * 16 + lg * 4 + reg;
                attn2[(size_t)r * DMODEL + h * HDIM + jd * 16 + lrow] = acco[jd][reg] * spv[reg];
            }
    } else {
        if (c == 0) {
#pragma unroll
            for (int jd = 0; jd < 8; ++jd)
#pragma unroll
                for (int reg = 0; reg < 4; ++reg) {
                    int r = q0 + w * 16 + lg * 4 + reg;
                    attn2[(size_t)r * DMODEL + h * HDIM + jd * 16 + lrow] = acco[jd][reg];
                }
        } else {
#pragma unroll
            for (int jd = 0; jd < 8; ++jd)
#pragma unroll
                for (int reg = 0; reg < 4; ++reg) {
                    int rr = w * 16 + lg * 4 + reg;
                    pp[(((size_t)h * 16 + (qb - 16)) * 64 + rr) * 128 + jd * 16 + lrow] =
                        acco[jd][reg];
                }
        }
        if (lrow == 0) {
            size_t zbase = (((size_t)h * 16 + (qb - 16)) * 2 + c) * 64;
#pragma unroll
            for (int reg = 0; reg < 4; ++reg)
                zb[zbase + w * 16 + lg * 4 + reg] = zt[reg];
        }
    }
}

// ---------------- reduce: out = (chunk0 + chunk1) * spv(Z0+Z1), tiles qb>=16 ----------------
__global__ __launch_bounds__(256) void attn_red_k(float* __restrict__ attn2,
        const float* __restrict__ pp, const float* __restrict__ zb) {
    int t16 = blockIdx.x, h = blockIdx.y;
    int qb = t16 + 16;
    int tid = threadIdx.x;
    for (int e = tid; e < 2048; e += 256) {
        int i = (e * 4) >> 7, j = (e * 4) & 127;
        float z0 = zb[(((size_t)h * 16 + t16) * 2 + 0) * 64 + i];
        float z1 = zb[(((size_t)h * 16 + t16) * 2 + 1) * 64 + i];
        float zinv = 1.0f / (z0 + z1);
        float spv = fmaxf(zinv / 127.0f, 1e-8f);
        float4 p = *(const float4*)&pp[(((size_t)h * 16 + t16) * 64 + i) * 128 + j];
        float* d = &attn2[(size_t)(qb * 64 + i) * DMODEL + h * HDIM + j];
        float4 dv = *(float4*)d;
        dv.x = (dv.x + p.x) * spv; dv.y = (dv.y + p.y) * spv;
        dv.z = (dv.z + p.z) * spv; dv.w = (dv.w + p.w) * spv;
        *(float4*)d = dv;
    }
}

extern "C" void kernel_launch(void* const* d_in, const int* in_sizes, int n_in,
                              void* d_out, int out_size, void* d_ws, size_t ws_size,
                              hipStream_t stream) {
    (void)in_sizes; (void)n_in; (void)out_size; (void)ws_size;
    const float* hidden = (const float*)d_in[0];
    const float* Wq = (const float*)d_in[1];
    const float* Wk = (const float*)d_in[2];
    const float* Wv = (const float*)d_in[3];
    const float* Wo = (const float*)d_in[4];
    const float* qw = (const float*)d_in[5];
    const float* kw = (const float*)d_in[6];
    const int* pos = (const int*)d_in[7];
    float* out = (float*)d_out;
    char* ws = (char*)d_ws;

    const size_t MB = 1024 * 1024;
    signed char* x_i8  = (signed char*)(ws);            // 4 MB (tiled) -> a_i8 reuse
    signed char* wq_i8 = (signed char*)(ws + 4 * MB);   // 8 MB stacked: wq(4)+wk(2)+wv(2)
    signed char* wk_i8 = (signed char*)(ws + 8 * MB);
    signed char* wv_i8 = (signed char*)(ws + 10 * MB);
    signed char* wo_i8 = (signed char*)(ws + 12 * MB);  // 4 MB
    signed char* q_i8  = (signed char*)(ws + 16 * MB);  // 4 MB (attn-tiled)
    signed char* k_i8  = (signed char*)(ws + 20 * MB);  // 2 MB (attn-tiled)
    float* sx  = (float*)(ws + 22 * MB);
    float* swq = sx + 2048;                             // swq/swk/swv contiguous (4096)
    float* swk = swq + 2048;
    float* swv = swk + 1024;
    float* swo = swv + 1024;
    float* sq  = swo + 2048;                            // 16*2048
    float* sk  = sq + NH * SEQ;                         // 8*2048
    float* sa  = sk + NKV * SEQ;                        // 2048
    float* inv_tab = sa + 2048;                         // 64
    float* ct  = (float*)(ws + 22 * MB + 512 * 1024);   // 512 KB
    float* st  = (float*)(ws + 22 * MB + 1024 * 1024);  // 512 KB
    float* qkv_lin = (float*)(ws + 24 * MB);            // 32 MB [S,4096]; dead after qkv_post
    unsigned short* vtT = (unsigned short*)(ws + 24 * MB);  // 8 MB (reuse)
    float* attn2 = (float*)(ws + 32 * MB);              // 16 MB (reuse)
    float* pp    = (float*)(ws + 48 * MB);              // 8 MB (reuse)
    float* v_dq  = (float*)(ws + 56 * MB);              // 8 MB; dead after vt_split
    float* mm    = (float*)(ws + 56 * MB);              // 512 KB (reuse of v_dq)
    float* zb    = (float*)(ws + 56 * MB + 512 * 1024); // 128 KB
    signed char* a_i8 = x_i8;

    rope_init_k<<<1, 64, 0, stream>>>(inv_tab);
    rope_tab_k<<<2048, 64, 0, stream>>>(pos, inv_tab, ct, st);
    row_quant_k<<<128, 256, 0, stream>>>(hidden, x_i8, sx, 2048);
    row_quant_k<<<128, 256, 0, stream>>>(Wq, wq_i8, swq, 2048);
    row_quant_k<<<64, 256, 0, stream>>>(Wk, wk_i8, swk, 2048);
    row_quant_k<<<64, 256, 0, stream>>>(Wv, wv_i8, swv, 2048);
    row_quant_k<<<128, 256, 0, stream>>>(Wo, wo_i8, swo, 2048);

    // fused QKV projection: B = stacked [4096 x 2048] tiled weights
    gemm_i8_k<<<dim3(32, 16), 256, 0, stream>>>(x_i8, sx, wq_i8, swq, qkv_lin, 2048, 4096, 2048);

    qkv_post_k<<<2048, 256, 0, stream>>>(qkv_lin, qw, kw, ct, st, q_i8, sq, k_i8, sk, v_dq);
    vt_split_k<<<dim3(32, 8), 256, 0, stream>>>(v_dq, vtT);

    attn_p1_k<<<dim3(128, 16), 256, 0, stream>>>(q_i8, sq, k_i8, sk, mm);
    attn_p2_k<<<dim3(64, 16), 256, 0, stream>>>(q_i8, sq, k_i8, sk, vtT, mm, attn2, pp, zb);
    attn_red_k<<<dim3(16, 16), 256, 0, stream>>>(attn2, pp, zb);

    row_quant_k<<<128, 256, 0, stream>>>(attn2, a_i8, sa, 2048);
    gemm_i8_k<<<dim3(16, 16), 256, 0, stream>>>(a_i8, sa, wo_i8, swo, out, 2048, 2048, 2048);
}

// Round 9
// 202.496 us; speedup vs baseline: 2.3389x; 1.3959x over previous
//
#include <hip/hip_runtime.h>
#include <math.h>

#define NH 16
#define NKV 8
#define HDIM 128
#define SEQ 2048
#define DMODEL 2048

typedef int   v4i __attribute__((ext_vector_type(4)));
typedef float v4f __attribute__((ext_vector_type(4)));
typedef __bf16 v8bf __attribute__((ext_vector_type(8)));

static constexpr float SM_SCALE = 0.08838834764831843f; // 128**-0.5

#define GLOBP(p) (__attribute__((address_space(1))) void*)(p)
#define LDSP(p)  (__attribute__((address_space(3))) void*)(p)
#define ASYNC16(g, l) __builtin_amdgcn_global_load_lds(GLOBP(g), LDSP(l), 16, 0, 0)

// Fragment-tiled i8 layout for X[R][K] (R%16==0, K%64==0):
// frag (r>>4, k>>6) is 1024B; within: byte = ((k>>4)&3)*256 + (r&15)*16 + (k&15).

// ---------------- merged per-row int8 quant for all 5 inputs ----------------
// ws layout makes the 5 tiled outputs contiguous (16MB) and the 5 scale arrays
// contiguous (8192 floats), so one 512-block launch covers everything.
__global__ __launch_bounds__(256) void quant_all_k(const float* __restrict__ hidden,
        const float* __restrict__ Wq, const float* __restrict__ Wk,
        const float* __restrict__ Wv, const float* __restrict__ Wo,
        signed char* __restrict__ out, float* __restrict__ scale) {
    int p = blockIdx.x;               // 16-row panel index, 512 total
    int row0g = p * 16;
    const float* in; int lr0;
    if (row0g < 2048)      { in = hidden; lr0 = row0g; }
    else if (row0g < 4096) { in = Wq; lr0 = row0g - 2048; }
    else if (row0g < 5120) { in = Wk; lr0 = row0g - 4096; }
    else if (row0g < 6144) { in = Wv; lr0 = row0g - 5120; }
    else                   { in = Wo; lr0 = row0g - 6144; }
    const int cols = 2048;
    int tid = threadIdx.x;
    __shared__ float srow[16];
    int r = tid >> 4, l16 = tid & 15;
    const float4* x4 = (const float4*)(in + (size_t)(lr0 + r) * cols);
    float amax = 0.f;
    for (int c4 = l16; c4 < (cols >> 2); c4 += 16) {
        float4 v = x4[c4];
        amax = fmaxf(amax, fmaxf(fmaxf(fabsf(v.x), fabsf(v.y)),
                                 fmaxf(fabsf(v.z), fabsf(v.w))));
    }
#pragma unroll
    for (int m = 1; m <= 8; m <<= 1) amax = fmaxf(amax, __shfl_xor(amax, m));
    if (l16 == 0) {
        float s = fmaxf(amax / 127.0f, 1e-8f);
        srow[r] = s;
        scale[row0g + r] = s;
    }
    __syncthreads();
    int total = (cols >> 4) * 16;
    size_t obase = (size_t)p * 32768;
    for (int idx = tid; idx < total; idx += 256) {
        int f = idx >> 6, q = (idx >> 4) & 3, rr = idx & 15;
        const float* src = in + (size_t)(lr0 + rr) * cols + f * 64 + q * 16;
        float s = srow[rr];
        unsigned int wds[4];
#pragma unroll
        for (int g = 0; g < 4; ++g) {
            float4 v = *(const float4*)(src + g * 4);
            int b0 = (int)fminf(fmaxf(rintf(v.x / s), -127.f), 127.f);
            int b1 = (int)fminf(fmaxf(rintf(v.y / s), -127.f), 127.f);
            int b2 = (int)fminf(fmaxf(rintf(v.z / s), -127.f), 127.f);
            int b3 = (int)fminf(fmaxf(rintf(v.w / s), -127.f), 127.f);
            wds[g] = (b0 & 255) | ((b1 & 255) << 8) | ((b2 & 255) << 16) | ((b3 & 255) << 24);
        }
        *(uint4*)(out + obase + (size_t)idx * 16) =
            make_uint4(wds[0], wds[1], wds[2], wds[3]);
    }
}

// ---------------- single-tensor row quant (for attn2) ----------------
__global__ __launch_bounds__(256) void row_quant_k(const float* __restrict__ in,
        signed char* __restrict__ out, float* __restrict__ scale, int cols) {
    int row0 = blockIdx.x * 16;
    int tid = threadIdx.x;
    __shared__ float srow[16];
    int r = tid >> 4, l16 = tid & 15;
    const float4* x4 = (const float4*)(in + (size_t)(row0 + r) * cols);
    float amax = 0.f;
    for (int c4 = l16; c4 < (cols >> 2); c4 += 16) {
        float4 v = x4[c4];
        amax = fmaxf(amax, fmaxf(fmaxf(fabsf(v.x), fabsf(v.y)),
                                 fmaxf(fabsf(v.z), fabsf(v.w))));
    }
#pragma unroll
    for (int m = 1; m <= 8; m <<= 1) amax = fmaxf(amax, __shfl_xor(amax, m));
    if (l16 == 0) {
        float s = fmaxf(amax / 127.0f, 1e-8f);
        srow[r] = s;
        scale[row0 + r] = s;
    }
    __syncthreads();
    int total = (cols >> 4) * 16;
    size_t obase = ((size_t)(row0 >> 4) * (cols >> 6)) << 10;
    for (int idx = tid; idx < total; idx += 256) {
        int f = idx >> 6, q = (idx >> 4) & 3, rr = idx & 15;
        const float* src = in + (size_t)(row0 + rr) * cols + f * 64 + q * 16;
        float s = srow[rr];
        unsigned int wds[4];
#pragma unroll
        for (int g = 0; g < 4; ++g) {
            float4 v = *(const float4*)(src + g * 4);
            int b0 = (int)fminf(fmaxf(rintf(v.x / s), -127.f), 127.f);
            int b1 = (int)fminf(fmaxf(rintf(v.y / s), -127.f), 127.f);
            int b2 = (int)fminf(fmaxf(rintf(v.z / s), -127.f), 127.f);
            int b3 = (int)fminf(fmaxf(rintf(v.w / s), -127.f), 127.f);
            wds[g] = (b0 & 255) | ((b1 & 255) << 8) | ((b2 & 255) << 16) | ((b3 & 255) << 24);
        }
        *(uint4*)(out + obase + (size_t)idx * 16) =
            make_uint4(wds[0], wds[1], wds[2], wds[3]);
    }
}

// ---------------- int8 GEMM on tiled A/B, double-buffered LDS ----------------
__global__ __launch_bounds__(256, 2) void gemm_i8_k(const signed char* __restrict__ A,
        const float* __restrict__ sa, const signed char* __restrict__ B,
        const float* __restrict__ sb, float* __restrict__ C, int M, int N, int K) {
    __shared__ __align__(16) signed char lsA[2][8192];
    __shared__ __align__(16) signed char lsB[2][8192];
    int tid = threadIdx.x;
    int w = tid >> 6, l = tid & 63;
    int wr = w >> 1, wc = w & 1;
    int lrow = l & 15;
    int m0 = blockIdx.y * 128, n0 = blockIdx.x * 128;
    int kb6 = K >> 6;
    v4i acc[4][4];
#pragma unroll
    for (int i = 0; i < 4; ++i)
#pragma unroll
        for (int j = 0; j < 4; ++j) acc[i][j] = (v4i){0, 0, 0, 0};

    auto stage = [&](int buf, int k6) {
#pragma unroll
        for (int a = 0; a < 2; ++a) {
            int f = a * 4 + w;
            ASYNC16(A + (((size_t)(((m0 >> 4) + f) * kb6 + k6)) << 10) + l * 16,
                    lsA[buf] + f * 1024);
            ASYNC16(B + (((size_t)(((n0 >> 4) + f) * kb6 + k6)) << 10) + l * 16,
                    lsB[buf] + f * 1024);
        }
    };

    stage(0, 0);
    asm volatile("s_waitcnt vmcnt(0)" ::: "memory");
    __syncthreads();
    int cur = 0;
    for (int t = 0; t < kb6; ++t) {
        if (t + 1 < kb6) stage(cur ^ 1, t + 1);
        v4i af[4], bf[4];
#pragma unroll
        for (int i = 0; i < 4; ++i) af[i] = *(const v4i*)(lsA[cur] + (wr * 4 + i) * 1024 + l * 16);
#pragma unroll
        for (int j = 0; j < 4; ++j) bf[j] = *(const v4i*)(lsB[cur] + (wc * 4 + j) * 1024 + l * 16);
#pragma unroll
        for (int i = 0; i < 4; ++i)
#pragma unroll
            for (int j = 0; j < 4; ++j)
                acc[i][j] = __builtin_amdgcn_mfma_i32_16x16x64_i8(af[i], bf[j], acc[i][j], 0, 0, 0);
        asm volatile("s_waitcnt vmcnt(0)" ::: "memory");
        __syncthreads();
        cur ^= 1;
    }
    int r0 = m0 + wr * 64, c0 = n0 + wc * 64;
    int lg = l >> 4;
    float sbv[4];
#pragma unroll
    for (int j = 0; j < 4; ++j) sbv[j] = sb[c0 + j * 16 + lrow];
#pragma unroll
    for (int i = 0; i < 4; ++i) {
        float4 s4 = *(const float4*)(sa + r0 + i * 16 + lg * 4);
        float sav[4] = {s4.x, s4.y, s4.z, s4.w};
#pragma unroll
        for (int j = 0; j < 4; ++j) {
#pragma unroll
            for (int reg = 0; reg < 4; ++reg) {
                int rr = r0 + i * 16 + lg * 4 + reg;
                C[(size_t)rr * N + c0 + j * 16 + lrow] = (float)acc[i][j][reg] * (sav[reg] * sbv[j]);
            }
        }
    }
}

// ---------------- rope tables ----------------
__global__ void rope_init_k(float* __restrict__ inv_tab) {
    int i = threadIdx.x; // 64
    inv_tab[i] = 1.0f / (float)pow(1.0e6, (double)i / 64.0);
}
__global__ void rope_tab_k(const int* __restrict__ pos_ids, const float* __restrict__ inv_tab,
                           float* __restrict__ ct, float* __restrict__ st) {
    int t = blockIdx.x;
    int fi = threadIdx.x; // 64
    float fr = (float)pos_ids[t] * inv_tab[fi];
    float sn, c;
    sincosf(fr, &sn, &c);
    ct[t * 64 + fi] = c;
    st[t * 64 + fi] = sn;
}

// ---------------- fused rmsnorm+rope+quant, barrier-free ----------------
__global__ __launch_bounds__(256) void qkv_post_k(const float* __restrict__ qkv_lin,
        const float* __restrict__ qw, const float* __restrict__ kw,
        const float* __restrict__ ct, const float* __restrict__ st,
        signed char* __restrict__ q_i8, float* __restrict__ sq,
        signed char* __restrict__ k_i8, float* __restrict__ sk,
        float* __restrict__ v_dq) {
    int t = blockIdx.x;
    int wv = threadIdx.x >> 6, l = threadIdx.x & 63;
    const float* row = qkv_lin + (size_t)t * 4096;
    float cth = ct[t * 64 + l];
    float sth = st[t * 64 + l];
    size_t ta0 = (size_t)(((t >> 4) * 2) << 10)
               + (size_t)((((l >> 4) & 3) << 8) + ((t & 15) << 4) + (l & 15));
    for (int slot = wv; slot < 32; slot += 4) {
        float x0 = row[slot * 128 + l];
        float x1 = row[slot * 128 + l + 64];
        if (slot < 24) {
            float ss = x0 * x0 + x1 * x1;
#pragma unroll
            for (int m = 1; m <= 32; m <<= 1) ss += __shfl_xor(ss, m);
            float rs = 1.0f / sqrtf(ss / 128.0f + 1e-6f);
            const float* wn = (slot < 16) ? qw : kw;
            x0 = (x0 * rs) * wn[l];
            x1 = (x1 * rs) * wn[l + 64];
            float nx0 = x0 * cth - x1 * sth;
            float nx1 = x1 * cth + x0 * sth;
            x0 = nx0; x1 = nx1;
        }
        float amax = fmaxf(fabsf(x0), fabsf(x1));
#pragma unroll
        for (int m = 1; m <= 32; m <<= 1) amax = fmaxf(amax, __shfl_xor(amax, m));
        float s = fmaxf(amax / 127.0f, 1e-8f);
        float q0 = fminf(fmaxf(rintf(x0 / s), -127.f), 127.f);
        float q1 = fminf(fmaxf(rintf(x1 / s), -127.f), 127.f);
        if (slot < 16) {
            signed char* dst = q_i8 + (size_t)slot * (SEQ * 128);
            dst[ta0] = (signed char)(int)q0;
            dst[ta0 + 1024] = (signed char)(int)q1;
            if (l == 0) sq[slot * SEQ + t] = s;
        } else if (slot < 24) {
            signed char* dst = k_i8 + (size_t)(slot - 16) * (SEQ * 128);
            dst[ta0] = (signed char)(int)q0;
            dst[ta0 + 1024] = (signed char)(int)q1;
            if (l == 0) sk[(slot - 16) * SEQ + t] = s;
        } else {
            float* dst = v_dq + ((size_t)(slot - 24) * SEQ + t) * HDIM;
            dst[l] = q0 * s;
            dst[l + 64] = q1 * s;
        }
    }
}

// ---------------- bf16 helpers ----------------
__device__ __forceinline__ unsigned int f2bf(float x) {
    unsigned int u = __float_as_uint(x);
    return (u + 0x7fffu + ((u >> 16) & 1u)) >> 16;
}
__device__ __forceinline__ float bf2f(unsigned int h) {
    return __uint_as_float(h << 16);
}

// ---------------- V transpose + bf16 split into MFMA-fragment-tiled vtT ----------------
__global__ __launch_bounds__(256) void vt_split_k(const float* __restrict__ v_dq,
        unsigned short* __restrict__ vtT) {
    int kv = blockIdx.y, kb = blockIdx.x;
    int t0 = kb * 64;
    __shared__ float tile[64][132];
    int tid = threadIdx.x;
    const float* src = v_dq + ((size_t)kv * SEQ + t0) * HDIM;
#pragma unroll
    for (int i = 0; i < 8; ++i) {
        int f4 = i * 256 + tid;
        int r = f4 >> 5, c = (f4 & 31) << 2;
        float4 v = *(const float4*)(src + r * HDIM + c);
        tile[r][c] = v.x; tile[r][c + 1] = v.y; tile[r][c + 2] = v.z; tile[r][c + 3] = v.w;
    }
    __syncthreads();
    int d = tid >> 1, th = (tid & 1) * 32;
    size_t base_hi = (size_t)(kv * 2 + 0) * (SEQ * 128);
    size_t base_lo = (size_t)(kv * 2 + 1) * (SEQ * 128);
#pragma unroll
    for (int j = 0; j < 32; j += 2) {
        int tl = th + j;
        float a = tile[tl][d], b = tile[tl + 1][d];
        unsigned int ah = f2bf(a), bh = f2bf(b);
        unsigned int al = f2bf(a - bf2f(ah)), bl = f2bf(b - bf2f(bh));
        int off = kb * 8192 + ((d >> 4) * 2 + ((tl >> 5) & 1)) * 512
                + (((d & 15) + (((tl >> 3) & 3) << 4)) << 3) + (tl & 7);
        *(unsigned int*)(vtT + base_hi + off) = ah | (bh << 16);
        *(unsigned int*)(vtT + base_lo + off) = al | (bl << 16);
    }
}

// ---------------- attention pass 1: GQA-paired (2 q-heads share K), max only ----------------
__global__ __launch_bounds__(256, 4) void attn_p1_k(const signed char* __restrict__ q_i8,
        const float* __restrict__ sq, const signed char* __restrict__ k_i8,
        const float* __restrict__ sk, float* __restrict__ mm) {
    int bx = blockIdx.x, hp = blockIdx.y;        // hp = kv head; q heads 2hp, 2hp+1
    int qb = 31 - (bx >> 2), c = bx & 3;
    int nch = (qb + 8) >> 3;
    if (c >= nch) return;
    int q0 = qb * 64;
    int kb0 = c * 8, kb1 = min((c + 1) * 8, qb + 1);
    int tid = threadIdx.x, w = tid >> 6, l = tid & 63;
    int lrow = l & 15, lg = l >> 4;
    int h0 = hp * 2, h1 = h0 + 1;

    const signed char* qtA = q_i8 + (size_t)h0 * (SEQ * 128)
                           + ((size_t)((((q0 >> 4) + w) * 2)) << 10) + l * 16;
    const signed char* qtB = qtA + (size_t)(SEQ * 128);
    v4i qfA0 = *(const v4i*)(qtA), qfA1 = *(const v4i*)(qtA + 1024);
    v4i qfB0 = *(const v4i*)(qtB), qfB1 = *(const v4i*)(qtB + 1024);
    float4 sA = *(const float4*)(sq + (size_t)h0 * SEQ + q0 + w * 16 + lg * 4);
    float4 sB = *(const float4*)(sq + (size_t)h1 * SEQ + q0 + w * 16 + lg * 4);
    float sqrA[4] = {sA.x, sA.y, sA.z, sA.w};
    float sqrB[4] = {sB.x, sB.y, sB.z, sB.w};
    const signed char* kbase = k_i8 + (size_t)hp * (SEQ * 128);
    const float* skb = sk + (size_t)hp * SEQ;

    float mA[4], mB[4];
#pragma unroll
    for (int r = 0; r < 4; ++r) { mA[r] = -1e30f; mB[r] = -1e30f; }

    v4i ka[8], kn[8];
    float skc[4], skn[4];
    auto loadK = [&](v4i* dst, float* sdst, int k0) {
#pragma unroll
        for (int f = 0; f < 8; ++f)
            dst[f] = *(const v4i*)(kbase + ((size_t)((k0 >> 4) * 2 + f) << 10) + l * 16);
#pragma unroll
        for (int j = 0; j < 4; ++j) sdst[j] = skb[k0 + j * 16 + lrow];
    };

    loadK(ka, skc, kb0 * 64);
    for (int kb = kb0; kb < kb1; ++kb) {
        if (kb + 1 < kb1) loadK(kn, skn, (kb + 1) * 64);
        int k0 = kb * 64;
        v4i sciA[4], sciB[4];
#pragma unroll
        for (int j = 0; j < 4; ++j) {
            v4i z = {0, 0, 0, 0};
            v4i tA = __builtin_amdgcn_mfma_i32_16x16x64_i8(qfA0, ka[j * 2], z, 0, 0, 0);
            sciA[j] = __builtin_amdgcn_mfma_i32_16x16x64_i8(qfA1, ka[j * 2 + 1], tA, 0, 0, 0);
            v4i tB = __builtin_amdgcn_mfma_i32_16x16x64_i8(qfB0, ka[j * 2], z, 0, 0, 0);
            sciB[j] = __builtin_amdgcn_mfma_i32_16x16x64_i8(qfB1, ka[j * 2 + 1], tB, 0, 0, 0);
        }
#pragma unroll
        for (int reg = 0; reg < 4; ++reg) {
            int r = q0 + w * 16 + lg * 4 + reg;
#pragma unroll
            for (int j = 0; j < 4; ++j) {
                bool ok = (k0 + j * 16 + lrow <= r);
                float ss = skc[j] * SM_SCALE;
                float svA = ((float)sciA[j][reg] * sqrA[reg]) * ss;
                float svB = ((float)sciB[j][reg] * sqrB[reg]) * ss;
                mA[reg] = fmaxf(mA[reg], ok ? svA : -1e30f);
                mB[reg] = fmaxf(mB[reg], ok ? svB : -1e30f);
            }
        }
        if (kb + 1 < kb1) {
#pragma unroll
            for (int f = 0; f < 8; ++f) ka[f] = kn[f];
#pragma unroll
            for (int j = 0; j < 4; ++j) skc[j] = skn[j];
        }
    }
#pragma unroll
    for (int reg = 0; reg < 4; ++reg) {
#pragma unroll
        for (int mask = 1; mask <= 8; mask <<= 1) {
            mA[reg] = fmaxf(mA[reg], __shfl_xor(mA[reg], mask));
            mB[reg] = fmaxf(mB[reg], __shfl_xor(mB[reg], mask));
        }
    }
    if (lrow == 0) {
        size_t bA = ((size_t)(h0 * 32 + qb) * 4 + c) * 64;
        size_t bB = ((size_t)(h1 * 32 + qb) * 4 + c) * 64;
#pragma unroll
        for (int reg = 0; reg < 4; ++reg) {
            mm[bA + w * 16 + lg * 4 + reg] = mA[reg];
            mm[bB + w * 16 + lg * 4 + reg] = mB[reg];
        }
    }
}

// NOTE on scale-multiplication order: sv = ((float)i * sqr) * (skc * SM_SCALE) here vs
// (((float)i * (sqr*skc)) * SM_SCALE) earlier — differs by ulps only; threshold margin 7x.

// ---------------- attention pass 2: GQA-paired split-K PV ----------------
// One block computes q-heads 2hp,2hp+1 over one (qb, chunk): K/V loads + barriers
// amortized over 2x compute. LDS: V dbuf 64K + K 8K + plds 8K = 80KB -> 2 blocks/CU.
__global__ __launch_bounds__(256, 2) void attn_p2_k(const signed char* __restrict__ q_i8,
        const float* __restrict__ sq, const signed char* __restrict__ k_i8,
        const float* __restrict__ sk, const unsigned short* __restrict__ vtT,
        const float* __restrict__ mm, float* __restrict__ attn2, float* __restrict__ pp,
        float* __restrict__ zb) {
    __shared__ __align__(16) unsigned short vlds[2][16384]; // 64 KB
    __shared__ __align__(16) signed char klds[8192];        // 8 KB
    __shared__ __align__(16) unsigned short plds[4096];     // 8 KB wave-private (A then B)
    int bx = blockIdx.x, hp = blockIdx.y;
    int qb = 31 - (bx >> 1), c = bx & 1;
    int nch2 = (qb >= 16) ? 2 : 1;
    if (c >= nch2) return;
    int q0 = qb * 64;
    int kb0 = c * 16, kb1 = min((c + 1) * 16, qb + 1);
    int tid = threadIdx.x, w = tid >> 6, l = tid & 63;
    int lrow = l & 15, lg = l >> 4;
    int h0 = hp * 2, h1 = h0 + 1;

    const signed char* qtA = q_i8 + (size_t)h0 * (SEQ * 128)
                           + ((size_t)((((q0 >> 4) + w) * 2)) << 10) + l * 16;
    const signed char* qtB = qtA + (size_t)(SEQ * 128);
    v4i qfA0 = *(const v4i*)(qtA), qfA1 = *(const v4i*)(qtA + 1024);
    v4i qfB0 = *(const v4i*)(qtB), qfB1 = *(const v4i*)(qtB + 1024);
    float4 sA = *(const float4*)(sq + (size_t)h0 * SEQ + q0 + w * 16 + lg * 4);
    float4 sB = *(const float4*)(sq + (size_t)h1 * SEQ + q0 + w * 16 + lg * 4);
    float sqrA[4] = {sA.x, sA.y, sA.z, sA.w};
    float sqrB[4] = {sB.x, sB.y, sB.z, sB.w};

    int nch1 = (qb + 8) >> 3;
    float mfA[4], mfB[4];
#pragma unroll
    for (int reg = 0; reg < 4; ++reg) {
        int r = w * 16 + lg * 4 + reg;
        float MA = -1e30f, MB = -1e30f;
        for (int c1 = 0; c1 < nch1; ++c1) {
            MA = fmaxf(MA, mm[((size_t)(h0 * 32 + qb) * 4 + c1) * 64 + r]);
            MB = fmaxf(MB, mm[((size_t)(h1 * 32 + qb) * 4 + c1) * 64 + r]);
        }
        mfA[reg] = MA; mfB[reg] = MB;
    }

    const signed char* kbase = k_i8 + (size_t)hp * (SEQ * 128);
    const float* skb = sk + (size_t)hp * SEQ;
    const unsigned short* vt_h = vtT + (size_t)(hp * 2 + 0) * (SEQ * 128);
    const unsigned short* vt_l = vtT + (size_t)(hp * 2 + 1) * (SEQ * 128);

    auto issueV = [&](int kb) {
        unsigned short* vb = &vlds[kb & 1][0];
#pragma unroll
        for (int a = 0; a < 8; ++a) {
            int fv = a * 4 + w;
            int sp_ = fv >> 4, fr = fv & 15;
            const unsigned short* vsrc = (sp_ ? vt_l : vt_h) + kb * 8192 + fr * 512 + l * 8;
            ASYNC16(vsrc, vb + fv * 512);
        }
    };
    auto issueK = [&](int kb) {
#pragma unroll
        for (int a = 0; a < 2; ++a) {
            int f = a * 4 + w;
            ASYNC16(kbase + ((size_t)(kb * 8 + f) << 10) + l * 16, klds + f * 1024);
        }
    };

    v4f accA[8], accB[8];
#pragma unroll
    for (int jd = 0; jd < 8; ++jd) {
        accA[jd] = (v4f){0.f, 0.f, 0.f, 0.f};
        accB[jd] = (v4f){0.f, 0.f, 0.f, 0.f};
    }
    float ztA[4] = {0.f, 0.f, 0.f, 0.f};
    float ztB[4] = {0.f, 0.f, 0.f, 0.f};

    issueV(kb0);
    issueK(kb0);
    asm volatile("s_waitcnt vmcnt(0)" ::: "memory");
    __syncthreads();
    for (int kb = kb0; kb < kb1; ++kb) {
        int k0 = kb * 64;
        v4i ka[8];
#pragma unroll
        for (int f = 0; f < 8; ++f)
            ka[f] = *(const v4i*)(klds + f * 1024 + l * 16);
        float skc[4];
#pragma unroll
        for (int j = 0; j < 4; ++j) skc[j] = skb[k0 + j * 16 + lrow];
        __syncthreads();        // all waves' klds reads drained -> safe to refill
        if (kb + 1 < kb1) {
            issueV(kb + 1);
            issueK(kb + 1);
        }
        v4i sciA[4], sciB[4];
#pragma unroll
        for (int j = 0; j < 4; ++j) {
            v4i z = {0, 0, 0, 0};
            v4i tA = __builtin_amdgcn_mfma_i32_16x16x64_i8(qfA0, ka[j * 2], z, 0, 0, 0);
            sciA[j] = __builtin_amdgcn_mfma_i32_16x16x64_i8(qfA1, ka[j * 2 + 1], tA, 0, 0, 0);
            v4i tB = __builtin_amdgcn_mfma_i32_16x16x64_i8(qfB0, ka[j * 2], z, 0, 0, 0);
            sciB[j] = __builtin_amdgcn_mfma_i32_16x16x64_i8(qfB1, ka[j * 2 + 1], tB, 0, 0, 0);
        }
        // softmax A -> plds -> regs; then B reuses the same wave-private region
#pragma unroll
        for (int reg = 0; reg < 4; ++reg) {
            int rq = lg * 4 + reg;
            int r = q0 + w * 16 + rq;
#pragma unroll
            for (int j = 0; j < 4; ++j) {
                int cc = j * 16 + lrow;
                float pd = 0.f;
                if (k0 + cc <= r) {
                    float sv = ((float)sciA[j][reg] * (sqrA[reg] * skc[j])) * SM_SCALE;
                    float e = __expf(sv - mfA[reg]);
                    ztA[reg] += e;
                    pd = fminf(rintf(127.0f * e), 127.f);
                }
                plds[(w * 2 + (cc >> 5)) * 512 + (rq + 16 * ((cc >> 3) & 3)) * 8 + (cc & 7)] =
                    (unsigned short)(__float_as_uint(pd) >> 16);
            }
        }
        v8bf pfA0 = *(const v8bf*)(plds + (w * 2 + 0) * 512 + l * 8);
        v8bf pfA1 = *(const v8bf*)(plds + (w * 2 + 1) * 512 + l * 8);
#pragma unroll
        for (int reg = 0; reg < 4; ++reg) {
            int rq = lg * 4 + reg;
            int r = q0 + w * 16 + rq;
#pragma unroll
            for (int j = 0; j < 4; ++j) {
                int cc = j * 16 + lrow;
                float pd = 0.f;
                if (k0 + cc <= r) {
                    float sv = ((float)sciB[j][reg] * (sqrB[reg] * skc[j])) * SM_SCALE;
                    float e = __expf(sv - mfB[reg]);
                    ztB[reg] += e;
                    pd = fminf(rintf(127.0f * e), 127.f);
                }
                plds[(w * 2 + (cc >> 5)) * 512 + (rq + 16 * ((cc >> 3) & 3)) * 8 + (cc & 7)] =
                    (unsigned short)(__float_as_uint(pd) >> 16);
            }
        }
        v8bf pfB0 = *(const v8bf*)(plds + (w * 2 + 0) * 512 + l * 8);
        v8bf pfB1 = *(const v8bf*)(plds + (w * 2 + 1) * 512 + l * 8);
        const unsigned short* vb = &vlds[kb & 1][0];
#pragma unroll
        for (int jd = 0; jd < 8; ++jd) {
            v8bf vh0 = *(const v8bf*)(vb + (jd * 2 + 0) * 512 + l * 8);
            v8bf vh1 = *(const v8bf*)(vb + (jd * 2 + 1) * 512 + l * 8);
            v8bf vl0 = *(const v8bf*)(vb + (16 + jd * 2 + 0) * 512 + l * 8);
            v8bf vl1 = *(const v8bf*)(vb + (16 + jd * 2 + 1) * 512 + l * 8);
            v4f tA = accA[jd];
            tA = __builtin_amdgcn_mfma_f32_16x16x32_bf16(pfA0, vh0, tA, 0, 0, 0);
            tA = __builtin_amdgcn_mfma_f32_16x16x32_bf16(pfA1, vh1, tA, 0, 0, 0);
            tA = __builtin_amdgcn_mfma_f32_16x16x32_bf16(pfA0, vl0, tA, 0, 0, 0);
            tA = __builtin_amdgcn_mfma_f32_16x16x32_bf16(pfA1, vl1, tA, 0, 0, 0);
            accA[jd] = tA;
            v4f tB = accB[jd];
            tB = __builtin_amdgcn_mfma_f32_16x16x32_bf16(pfB0, vh0, tB, 0, 0, 0);
            tB = __builtin_amdgcn_mfma_f32_16x16x32_bf16(pfB1, vh1, tB, 0, 0, 0);
            tB = __builtin_amdgcn_mfma_f32_16x16x32_bf16(pfB0, vl0, tB, 0, 0, 0);
            tB = __builtin_amdgcn_mfma_f32_16x16x32_bf16(pfB1, vl1, tB, 0, 0, 0);
            accB[jd] = tB;
        }
        asm volatile("s_waitcnt vmcnt(0)" ::: "memory");
        __syncthreads();
    }
#pragma unroll
    for (int reg = 0; reg < 4; ++reg) {
#pragma unroll
        for (int mask = 1; mask <= 8; mask <<= 1) {
            ztA[reg] += __shfl_xor(ztA[reg], mask);
            ztB[reg] += __shfl_xor(ztB[reg], mask);
        }
    }
    if (qb < 16) {
        float spA[4], spB[4];
#pragma unroll
        for (int reg = 0; reg < 4; ++reg) {
            spA[reg] = fmaxf((1.0f / ztA[reg]) / 127.0f, 1e-8f);
            spB[reg] = fmaxf((1.0f / ztB[reg]) / 127.0f, 1e-8f);
        }
#pragma unroll
        for (int jd = 0; jd < 8; ++jd)
#pragma unroll
            for (int reg = 0; reg < 4; ++reg) {
                int r = q0 + w * 16 + lg * 4 + reg;
                attn2[(size_t)r * DMODEL + h0 * HDIM + jd * 16 + lrow] = accA[jd][reg] * spA[reg];
                attn2[(size_t)r * DMODEL + h1 * HDIM + jd * 16 + lrow] = accB[jd][reg] * spB[reg];
            }
    } else {
        if (c == 0) {
#pragma unroll
            for (int jd = 0; jd < 8; ++jd)
#pragma unroll
                for (int reg = 0; reg < 4; ++reg) {
                    int r = q0 + w * 16 + lg * 4 + reg;
                    attn2[(size_t)r * DMODEL + h0 * HDIM + jd * 16 + lrow] = accA[jd][reg];
                    attn2[(size_t)r * DMODEL + h1 * HDIM + jd * 16 + lrow] = accB[jd][reg];
                }
        } else {
#pragma unroll
            for (int jd = 0; jd < 8; ++jd)
#pragma unroll
                for (int reg = 0; reg < 4; ++reg) {
                    int rr = w * 16 + lg * 4 + reg;
                    pp[(((size_t)h0 * 16 + (qb - 16)) * 64 + rr) * 128 + jd * 16 + lrow] = accA[jd][reg];
                    pp[(((size_t)h1 * 16 + (qb - 16)) * 64 + rr) * 128 + jd * 16 + lrow] = accB[jd][reg];
                }
        }
        if (lrow == 0) {
            size_t zA = (((size_t)h0 * 16 + (qb - 16)) * 2 + c) * 64;
            size_t zB = (((size_t)h1 * 16 + (qb - 16)) * 2 + c) * 64;
#pragma unroll
            for (int reg = 0; reg < 4; ++reg) {
                zb[zA + w * 16 + lg * 4 + reg] = ztA[reg];
                zb[zB + w * 16 + lg * 4 + reg] = ztB[reg];
            }
        }
    }
}

// ---------------- reduce: out = (chunk0 + chunk1) * spv(Z0+Z1), tiles qb>=16 ----------------
__global__ __launch_bounds__(256) void attn_red_k(float* __restrict__ attn2,
        const float* __restrict__ pp, const float* __restrict__ zb) {
    int t16 = blockIdx.x, h = blockIdx.y;
    int qb = t16 + 16;
    int tid = threadIdx.x;
    for (int e = tid; e < 2048; e += 256) {
        int i = (e * 4) >> 7, j = (e * 4) & 127;
        float z0 = zb[(((size_t)h * 16 + t16) * 2 + 0) * 64 + i];
        float z1 = zb[(((size_t)h * 16 + t16) * 2 + 1) * 64 + i];
        float zinv = 1.0f / (z0 + z1);
        float spv = fmaxf(zinv / 127.0f, 1e-8f);
        float4 p = *(const float4*)&pp[(((size_t)h * 16 + t16) * 64 + i) * 128 + j];
        float* d = &attn2[(size_t)(qb * 64 + i) * DMODEL + h * HDIM + j];
        float4 dv = *(float4*)d;
        dv.x = (dv.x + p.x) * spv; dv.y = (dv.y + p.y) * spv;
        dv.z = (dv.z + p.z) * spv; dv.w = (dv.w + p.w) * spv;
        *(float4*)d = dv;
    }
}

extern "C" void kernel_launch(void* const* d_in, const int* in_sizes, int n_in,
                              void* d_out, int out_size, void* d_ws, size_t ws_size,
                              hipStream_t stream) {
    (void)in_sizes; (void)n_in; (void)out_size; (void)ws_size;
    const float* hidden = (const float*)d_in[0];
    const float* Wq = (const float*)d_in[1];
    const float* Wk = (const float*)d_in[2];
    const float* Wv = (const float*)d_in[3];
    const float* Wo = (const float*)d_in[4];
    const float* qw = (const float*)d_in[5];
    const float* kw = (const float*)d_in[6];
    const int* pos = (const int*)d_in[7];
    float* out = (float*)d_out;
    char* ws = (char*)d_ws;

    const size_t MB = 1024 * 1024;
    signed char* x_i8  = (signed char*)(ws);            // contiguous 16MB tiled i8 block:
    signed char* wq_i8 = (signed char*)(ws + 4 * MB);   //   x(4) wq(4) wk(2) wv(2) wo(4)
    signed char* wo_i8 = (signed char*)(ws + 12 * MB);
    signed char* q_i8  = (signed char*)(ws + 16 * MB);  // 4 MB (attn-tiled)
    signed char* k_i8  = (signed char*)(ws + 20 * MB);  // 2 MB (attn-tiled)
    float* sx  = (float*)(ws + 22 * MB);                // contiguous scales (8192 floats):
    float* swq = sx + 2048;                             //   sx swq swk swv swo
    float* swo = sx + 6144;
    float* sq  = sx + 8192;                             // 16*2048
    float* sk  = sq + NH * SEQ;                         // 8*2048
    float* sa  = sk + NKV * SEQ;                        // 2048
    float* inv_tab = sa + 2048;                         // 64
    float* ct  = (float*)(ws + 22 * MB + 512 * 1024);   // 512 KB
    float* st  = (float*)(ws + 22 * MB + 1024 * 1024);  // 512 KB
    float* qkv_lin = (float*)(ws + 24 * MB);            // 32 MB [S,4096]; dead after qkv_post
    unsigned short* vtT = (unsigned short*)(ws + 24 * MB);  // 8 MB (reuse)
    float* attn2 = (float*)(ws + 32 * MB);              // 16 MB (reuse)
    float* pp    = (float*)(ws + 48 * MB);              // 8 MB (reuse)
    float* v_dq  = (float*)(ws + 56 * MB);              // 8 MB; dead after vt_split
    float* mm    = (float*)(ws + 56 * MB);              // 512 KB (reuse of v_dq)
    float* zb    = (float*)(ws + 56 * MB + 512 * 1024); // 128 KB
    signed char* a_i8 = x_i8;

    rope_init_k<<<1, 64, 0, stream>>>(inv_tab);
    rope_tab_k<<<2048, 64, 0, stream>>>(pos, inv_tab, ct, st);
    quant_all_k<<<512, 256, 0, stream>>>(hidden, Wq, Wk, Wv, Wo, x_i8, sx);

    // fused QKV projection: B = stacked [4096 x 2048] tiled weights
    gemm_i8_k<<<dim3(32, 16), 256, 0, stream>>>(x_i8, sx, wq_i8, swq, qkv_lin, 2048, 4096, 2048);

    qkv_post_k<<<2048, 256, 0, stream>>>(qkv_lin, qw, kw, ct, st, q_i8, sq, k_i8, sk, v_dq);
    vt_split_k<<<dim3(32, 8), 256, 0, stream>>>(v_dq, vtT);

    attn_p1_k<<<dim3(128, 8), 256, 0, stream>>>(q_i8, sq, k_i8, sk, mm);
    attn_p2_k<<<dim3(64, 8), 256, 0, stream>>>(q_i8, sq, k_i8, sk, vtT, mm, attn2, pp, zb);
    attn_red_k<<<dim3(16, 16), 256, 0, stream>>>(attn2, pp, zb);

    row_quant_k<<<128, 256, 0, stream>>>(attn2, a_i8, sa, 2048);
    gemm_i8_k<<<dim3(16, 16), 256, 0, stream>>>(a_i8, sa, wo_i8, swo, out, 2048, 2048, 2048);
}